// Round 7
// baseline (251.596 us; speedup 1.0000x reference)
//
#include <hip/hip_runtime.h>

typedef __bf16 bf16_t;
typedef __bf16 bf16x8 __attribute__((ext_vector_type(8)));
typedef float  f32x4  __attribute__((ext_vector_type(4)));
typedef float  f32x16 __attribute__((ext_vector_type(16)));
typedef unsigned u32x4 __attribute__((ext_vector_type(4)));

#define DIMM  1024
#define NHEAD 16
#define HDIM  64
#define BATCH 4
#define SEQ   2048
#define MROWS (BATCH*SEQ)   // 8192

#define AQB   128           // q rows per attn block
#define AKV   64            // kv per tile
#define NP    (SEQ/AQB)     // 16 q-blocks
#define SKS   72            // LDS row stride (elems), 144B, 16B-aligned
#define LOG2E 1.44269504088896f

__device__ __forceinline__ void gload_lds16(const bf16_t* g, bf16_t* l) {
  __builtin_amdgcn_global_load_lds(
      (const __attribute__((address_space(1))) void*)g,
      (__attribute__((address_space(3))) void*)l, 16, 0, 0);
}

__device__ __forceinline__ unsigned short f2bu(float f) {
  bf16_t b = (bf16_t)f;
  return __builtin_bit_cast(unsigned short, b);
}
__device__ __forceinline__ float bu2f(unsigned short u) {
  return __uint_as_float(((unsigned)u) << 16);
}
__device__ __forceinline__ unsigned packbf(float a, float b) {
  return (unsigned)f2bu(a) | ((unsigned)f2bu(b) << 16);
}
__device__ __forceinline__ float fexp2(float x) {   // v_exp_f32 = 2^x
  float r; asm("v_exp_f32 %0, %1" : "=v"(r) : "v"(x)); return r;
}

// ---------------- fp32 -> bf16 flat convert (4 elems/thread) ----------------
__global__ void k_convert(const float* __restrict__ in, bf16_t* __restrict__ out, int n4) {
  int i = blockIdx.x * blockDim.x + threadIdx.x;
  if (i >= n4) return;
  float4 v = reinterpret_cast<const float4*>(in)[i];
  ushort4 o;
  o.x = f2bu(v.x); o.y = f2bu(v.y); o.z = f2bu(v.z); o.w = f2bu(v.w);
  reinterpret_cast<ushort4*>(out)[i] = o;
}

// ------------- fp32 [R][C] -> bf16 [C][R] tiled transpose-convert -----------
__global__ void k_transpose_convert(const float* __restrict__ in, bf16_t* __restrict__ out,
                                    int R, int C) {
  __shared__ float tile[32][33];
  int cb = blockIdx.x * 32, rb = blockIdx.y * 32;
  int tx = threadIdx.x, ty = threadIdx.y;
  #pragma unroll
  for (int i = 0; i < 4; ++i)
    tile[ty + i*8][tx] = in[(size_t)(rb + ty + i*8) * C + cb + tx];
  __syncthreads();
  #pragma unroll
  for (int i = 0; i < 4; ++i)
    out[(size_t)(cb + ty + i*8) * R + rb + tx] = (bf16_t)tile[tx][ty + i*8];
}

// ---------------- RoPE cos/sin table [SEQ][32], fp64 trig ------------------
__global__ void k_rope_table(float* __restrict__ cosT, float* __restrict__ sinT) {
  int id = blockIdx.x * blockDim.x + threadIdx.x;
  if (id >= SEQ * 32) return;
  int t = id >> 5, i = id & 31;
  double ang = (double)t * pow(10000.0, -(double)i / 32.0);
  cosT[id] = (float)cos(ang);
  sinT[id] = (float)sin(ang);
}

// --- RoPE in-place on Q,K; Q additionally * 0.125*log2(e) (exp2-domain) ----
__global__ void k_rope(bf16_t* __restrict__ Q, bf16_t* __restrict__ Kb,
                       const float* __restrict__ cosT, const float* __restrict__ sinT) {
  int id = blockIdx.x * blockDim.x + threadIdx.x;  // (bh*SEQ + t)*32 + i
  if (id >= 64 * SEQ * 32) return;
  int i = id & 31;
  int t = (id >> 5) & (SEQ - 1);
  float c = cosT[(t << 5) + i], s = sinT[(t << 5) + i];
  unsigned* Qu = reinterpret_cast<unsigned*>(Q);
  unsigned* Ku = reinterpret_cast<unsigned*>(Kb);
  const float qs = 0.125f * LOG2E;
  {
    unsigned u = Qu[id];
    float x1 = bu2f((unsigned short)(u & 0xffffu));
    float x2 = bu2f((unsigned short)(u >> 16));
    Qu[id] = packbf((x1 * c - x2 * s) * qs, (x2 * c + x1 * s) * qs);
  }
  {
    unsigned u = Ku[id];
    float x1 = bu2f((unsigned short)(u & 0xffffu));
    float x2 = bu2f((unsigned short)(u >> 16));
    Ku[id] = packbf(x1 * c - x2 * s, x2 * c + x1 * s);
  }
}

// --------------- bf16 GEMM C = A[M][K] * BT[N][K]^T + bias -----------------
// MODE 0: scatter to q/k/v head layout (bf16).  MODE 1: fp32 out [M][N].
template<int MODE>
__global__ __launch_bounds__(256) void k_gemm(
    const bf16_t* __restrict__ A, const bf16_t* __restrict__ BT,
    const float* __restrict__ bias,
    bf16_t* __restrict__ q, bf16_t* __restrict__ k, bf16_t* __restrict__ v,
    float* __restrict__ outf, int M, int N, int K)
{
  __shared__ bf16_t sA[128 * 32];
  __shared__ bf16_t sB[128 * 32];
  const int tid = threadIdx.x;
  const int w = tid >> 6, lane = tid & 63;
  const int wr = w >> 1, wc = w & 1;
  const int l15 = lane & 15, l4 = lane >> 4;

  // bijective XCD swizzle (grids are multiples of 8)
  int nwg = gridDim.x * gridDim.y;
  int id  = blockIdx.y * gridDim.x + blockIdx.x;
  int cpx = nwg >> 3;
  int sid = (id & 7) * cpx + (id >> 3);
  int bx = sid % gridDim.x, by = sid / gridDim.x;

  const int rowA0 = by * 128;
  const int colB0 = bx * 128;

  f32x4 acc[4][4] = {};

  const int nkt = K >> 5;
  for (int kt = 0; kt < nkt; ++kt) {
    __syncthreads();
    #pragma unroll
    for (int i = 0; i < 2; ++i) {
      int c = i * 256 + w * 64 + lane;          // chunk id, 512 per tile
      int row = c >> 2, k8 = (c & 3) * 8;
      gload_lds16(A  + (size_t)(rowA0 + row) * K + kt * 32 + k8, sA + (i * 256 + w * 64) * 8);
      gload_lds16(BT + (size_t)(colB0 + row) * K + kt * 32 + k8, sB + (i * 256 + w * 64) * 8);
    }
    asm volatile("s_waitcnt vmcnt(0)" ::: "memory");
    __syncthreads();
    bf16x8 af[4], bfr[4];
    #pragma unroll
    for (int mi = 0; mi < 4; ++mi)
      af[mi] = *reinterpret_cast<const bf16x8*>(sA + (wr * 64 + mi * 16 + l15) * 32 + l4 * 8);
    #pragma unroll
    for (int ni = 0; ni < 4; ++ni)
      bfr[ni] = *reinterpret_cast<const bf16x8*>(sB + (wc * 64 + ni * 16 + l15) * 32 + l4 * 8);
    #pragma unroll
    for (int mi = 0; mi < 4; ++mi)
      #pragma unroll
      for (int ni = 0; ni < 4; ++ni)
        acc[mi][ni] = __builtin_amdgcn_mfma_f32_16x16x32_bf16(af[mi], bfr[ni], acc[mi][ni], 0, 0, 0);
  }

  #pragma unroll
  for (int mi = 0; mi < 4; ++mi) {
    #pragma unroll
    for (int ni = 0; ni < 4; ++ni) {
      int n = colB0 + wc * 64 + ni * 16 + l15;
      float bs = bias[n];
      #pragma unroll
      for (int r = 0; r < 4; ++r) {
        int m = rowA0 + wr * 64 + mi * 16 + l4 * 4 + r;
        float val = acc[mi][ni][r] + bs;
        if (MODE == 0) {
          int which = n >> 10, hd = n & 1023;
          int h = hd >> 6, d = hd & 63;
          int b = m >> 11, t = m & 2047;
          bf16_t* dst = (which == 0) ? q : (which == 1) ? k : v;
          dst[((size_t)(b * NHEAD + h) * SEQ + t) * HDIM + d] = (bf16_t)val;
        } else {
          outf[(size_t)m * N + n] = val;
        }
      }
    }
  }
}

// ------------- causal flash attention: swapped-operand 32x32 ----------------
// 4 waves x 32 q cols each (QBLK=128), KVBLK=64, double-buffered K/V^T LDS.
// S^T = mfma(K,Q): lane owns P[*][q=lane&31] -> in-register softmax in
// exp2-domain (log2e folded into Q). Half-exchanges via __shfl_xor(...,32).
// O^T = mfma(V^T, P). Epilogue sO aliases sK. LDS 36864B + VGPR 92 -> 4
// blocks/CU. Grid is UNPAIRED (1024 blocks, qblk = 15-blockIdx.x longest
// first): R6 showed the paired 512-block grid capped residency at 2
// blocks/CU (Occupancy 19.7%, VALUBusy 50%) -- grid-limited, not resources.
__global__ __launch_bounds__(256, 2) void k_attn(
    const bf16_t* __restrict__ Q, const bf16_t* __restrict__ Kb,
    const bf16_t* __restrict__ Vb, bf16_t* __restrict__ O)
{
  __shared__ bf16_t sK[2][64 * SKS];
  __shared__ bf16_t sV[2][64 * SKS];   // V^T: [d][kv]

  const int tid = threadIdx.x;
  const int w = tid >> 6, lane = tid & 63;
  const int l31 = lane & 31, hi = lane >> 5;
  const int bh = blockIdx.y;
  const size_t hbase = (size_t)bh * SEQ * HDIM;
  const int b = bh >> 4, h = bh & 15;
  const int srow = tid >> 3, sslot = tid & 7;

  const int qblk = NP - 1 - blockIdx.x;   // longest blocks dispatch first
  const int qbase = qblk * AQB + 32 * w;
  const int nt = 2 * qblk + 2;

  // Q fragments (pre-scaled by 0.125*log2e): B-op, n=q=l31, k=kt*16+8*hi+j
  bf16x8 qf[4];
  #pragma unroll
  for (int kt = 0; kt < 4; ++kt)
    qf[kt] = *reinterpret_cast<const bf16x8*>(
        Q + hbase + (size_t)(qbase + l31) * HDIM + kt * 16 + hi * 8);
  asm volatile("s_waitcnt vmcnt(0)" ::: "memory");
  asm volatile("" : "+v"(qf[0]), "+v"(qf[1]), "+v"(qf[2]), "+v"(qf[3]));

  u32x4 kr[2], vr[2];
  auto issue = [&](int t) {
    const bf16_t* kp = Kb + hbase + (size_t)(t * AKV + srow) * HDIM + sslot * 8;
    const bf16_t* vp = Vb + hbase + (size_t)(t * AKV + srow) * HDIM + sslot * 8;
    asm volatile("global_load_dwordx4 %0, %1, off" : "=v"(kr[0]) : "v"(kp));
    asm volatile("global_load_dwordx4 %0, %1, off" : "=v"(kr[1]) : "v"(kp + 32 * HDIM));
    asm volatile("global_load_dwordx4 %0, %1, off" : "=v"(vr[0]) : "v"(vp));
    asm volatile("global_load_dwordx4 %0, %1, off" : "=v"(vr[1]) : "v"(vp + 32 * HDIM));
  };
  auto stage = [&](int nb) {
    #pragma unroll
    for (int cc = 0; cc < 2; ++cc) {
      int row = srow + 32 * cc;                  // kv row
      *reinterpret_cast<u32x4*>(&sK[nb][row * SKS + ((sslot ^ (row >> 3)) << 3)]) = kr[cc];
      bf16x8 vv = __builtin_bit_cast(bf16x8, vr[cc]);
      #pragma unroll
      for (int j = 0; j < 8; ++j) {
        int d = sslot * 8 + j;
        sV[nb][d * SKS + (((row >> 3) ^ sslot) << 3) + (row & 7)] = vv[j];
      }
    }
  };

  float mrun = -1e30f, lrun = 0.f;   // per lane: q = qbase + l31 (log2 domain)
  f32x16 accO[2] = {};               // O^T: d = 32*dt + (r&3)+8*(r>>2)+4*hi, q = l31

  // prologue
  issue(0);
  asm volatile("s_waitcnt vmcnt(0)" ::: "memory");
  stage(0);
  issue(1);
  asm volatile("s_waitcnt lgkmcnt(0)" ::: "memory");
  __builtin_amdgcn_s_barrier();
  asm volatile("" ::: "memory");

  for (int t = 0; t < nt; ++t) {
    const int c = t & 1;
    if (t + 1 < nt) {
      asm volatile("s_waitcnt vmcnt(0)" ::: "memory");
      stage(c ^ 1);
      if (t + 2 < nt) issue(t + 2);
    }
    const bool masked = (t * AKV + AKV - 1 > qbase);   // wave-uniform
    #pragma unroll
    for (int sub = 0; sub < 2; ++sub) {
      // S^T = K x Q : D[kv][q]  (log2-domain logits)
      f32x16 sc = {};
      __builtin_amdgcn_s_setprio(1);
      #pragma unroll
      for (int kt = 0; kt < 4; ++kt) {
        int krow = 32 * sub + l31;
        bf16x8 kf = *reinterpret_cast<const bf16x8*>(
            &sK[c][krow * SKS + (((2 * kt + hi) ^ (krow >> 3)) << 3)]);
        sc = __builtin_amdgcn_mfma_f32_32x32x16_bf16(kf, qf[kt], sc, 0, 0, 0);
      }
      __builtin_amdgcn_s_setprio(0);

      // in-register softmax over kv (rows in regs; q = l31 lane-local)
      float p[16];
      const int qa = qbase + l31;
      const int kb0 = t * AKV + 32 * sub + 4 * hi;
      #pragma unroll
      for (int r = 0; r < 16; ++r) {
        float s = sc[r];
        if (masked) {
          int kvi = kb0 + (r & 3) + 8 * (r >> 2);
          if (kvi > qa) s = -1e30f;
        }
        p[r] = s;
      }
      // max tree (max3-fusable)
      float m0 = fmaxf(fmaxf(p[0],  p[1]),  p[2]);
      float m1 = fmaxf(fmaxf(p[3],  p[4]),  p[5]);
      float m2 = fmaxf(fmaxf(p[6],  p[7]),  p[8]);
      float m3 = fmaxf(fmaxf(p[9],  p[10]), p[11]);
      float m4 = fmaxf(fmaxf(p[12], p[13]), p[14]);
      float mt = fmaxf(fmaxf(fmaxf(m0, m1), fmaxf(m2, m3)), fmaxf(m4, p[15]));
      mt = fmaxf(mt, __shfl_xor(mt, 32));            // cross-half max
      if (!__all(mt <= mrun + 11.54f)) {             // T13 defer-max (8*log2e)
        float mnew = fmaxf(mrun, mt);
        float scl = fexp2(mrun - mnew);
        mrun = mnew;
        lrun *= scl;
        #pragma unroll
        for (int i = 0; i < 16; ++i) { accO[0][i] *= scl; accO[1][i] *= scl; }
      }
      float rs = 0.f;
      #pragma unroll
      for (int r = 0; r < 16; ++r) { p[r] = fexp2(p[r] - mrun); rs += p[r]; }
      lrun += rs + __shfl_xor(rs, 32);

      // pack P to bf16 B-fragments; half-exchange via shfl_xor(32).
      bf16x8 pf[2];
      #pragma unroll
      for (int kt = 0; kt < 2; ++kt) {
        unsigned P01 = packbf(p[8*kt+0], p[8*kt+1]);   // rows 16kt+(0,1)+4hi
        unsigned P23 = packbf(p[8*kt+2], p[8*kt+3]);   // rows 16kt+(2,3)+4hi
        unsigned P45 = packbf(p[8*kt+4], p[8*kt+5]);   // rows 16kt+(8,9)+4hi
        unsigned P67 = packbf(p[8*kt+6], p[8*kt+7]);   // rows 16kt+(10,11)+4hi
        unsigned ra = __shfl_xor(hi == 0 ? P45 : P01, 32);
        unsigned rb = __shfl_xor(hi == 0 ? P67 : P23, 32);
        unsigned dw0 = hi == 0 ? P01 : ra;   // rows (0,1) / (8,9)
        unsigned dw1 = hi == 0 ? P23 : rb;   // rows (2,3) / (10,11)
        unsigned dw2 = hi == 0 ? ra : P45;   // rows (4,5) / (12,13)
        unsigned dw3 = hi == 0 ? rb : P67;   // rows (6,7) / (14,15)
        pf[kt] = __builtin_bit_cast(bf16x8, (u32x4){dw0, dw1, dw2, dw3});
      }

      // O^T += V^T x P : D[d][q]
      __builtin_amdgcn_s_setprio(1);
      #pragma unroll
      for (int dt = 0; dt < 2; ++dt) {
        #pragma unroll
        for (int kt = 0; kt < 2; ++kt) {
          int vrow = 32 * dt + l31;
          bf16x8 vf = *reinterpret_cast<const bf16x8*>(
              &sV[c][vrow * SKS + (((4 * sub + 2 * kt + hi) ^ (vrow >> 3)) << 3)]);
          accO[dt] = __builtin_amdgcn_mfma_f32_32x32x16_bf16(vf, pf[kt], accO[dt], 0, 0, 0);
        }
      }
      __builtin_amdgcn_s_setprio(0);
    }
    asm volatile("s_waitcnt lgkmcnt(0)" ::: "memory");
    __builtin_amdgcn_s_barrier();
    asm volatile("" ::: "memory");
  }

  // epilogue: transpose O^T -> O via per-wave LDS region aliased onto sK
  // (safe: final barrier above means all sK reads are done; per-wave region)
  bf16_t* sOw = &sK[0][0] + w * (32 * SKS);
  float inv = 1.f / lrun;
  #pragma unroll
  for (int dt = 0; dt < 2; ++dt)
    #pragma unroll
    for (int r = 0; r < 16; ++r) {
      int d = 32 * dt + (r & 3) + 8 * (r >> 2) + 4 * hi;
      sOw[l31 * SKS + (d ^ ((l31 >> 3) << 3))] = (bf16_t)(accO[dt][r] * inv);
    }
  #pragma unroll
  for (int i = 0; i < 4; ++i) {
    int qr = 8 * i + (lane >> 3);
    int ch = lane & 7;
    bf16x8 vvv = *reinterpret_cast<const bf16x8*>(
        &sOw[qr * SKS + ((ch ^ (qr >> 3)) << 3)]);
    *reinterpret_cast<bf16x8*>(
        O + ((size_t)(b * SEQ + qbase + qr)) * DIMM + h * HDIM + ch * 8) = vvv;
  }
}

// ---------------------------------------------------------------------------
extern "C" void kernel_launch(void* const* d_in, const int* in_sizes, int n_in,
                              void* d_out, int out_size, void* d_ws, size_t ws_size,
                              hipStream_t stream) {
  const float* x     = (const float*)d_in[0];
  // d_in[1] = mask (causal tril) — structure hardcoded
  const float* qkv_w = (const float*)d_in[2];
  const float* qkv_b = (const float*)d_in[3];
  const float* out_w = (const float*)d_in[4];
  const float* out_b = (const float*)d_in[5];
  float* out = (float*)d_out;

  char* ws = (char*)d_ws;
  size_t off = 0;
  auto alloc = [&](size_t bytes) {
    char* p = ws + off;
    off += (bytes + 255) & ~(size_t)255;
    return (void*)p;
  };
  bf16_t* Xb    = (bf16_t*)alloc((size_t)MROWS * DIMM * 2);
  bf16_t* WqkvT = (bf16_t*)alloc((size_t)3 * DIMM * DIMM * 2);
  bf16_t* WoutT = (bf16_t*)alloc((size_t)DIMM * DIMM * 2);
  bf16_t* Qh    = (bf16_t*)alloc((size_t)64 * SEQ * HDIM * 2);
  bf16_t* Kh    = (bf16_t*)alloc((size_t)64 * SEQ * HDIM * 2);
  bf16_t* Vh    = (bf16_t*)alloc((size_t)64 * SEQ * HDIM * 2);
  bf16_t* AO    = (bf16_t*)alloc((size_t)MROWS * DIMM * 2);
  float*  cosT  = (float*)alloc((size_t)SEQ * 32 * 4);
  float*  sinT  = (float*)alloc((size_t)SEQ * 32 * 4);

  k_convert<<<(MROWS * DIMM / 4 + 255) / 256, 256, 0, stream>>>(x, Xb, MROWS * DIMM / 4);
  k_transpose_convert<<<dim3(3 * DIMM / 32, DIMM / 32), dim3(32, 8), 0, stream>>>(qkv_w, WqkvT, DIMM, 3 * DIMM);
  k_transpose_convert<<<dim3(DIMM / 32, DIMM / 32), dim3(32, 8), 0, stream>>>(out_w, WoutT, DIMM, DIMM);
  k_rope_table<<<(SEQ * 32 + 255) / 256, 256, 0, stream>>>(cosT, sinT);

  k_gemm<0><<<dim3(3 * DIMM / 128, MROWS / 128), 256, 0, stream>>>(
      Xb, WqkvT, qkv_b, Qh, Kh, Vh, nullptr, MROWS, 3 * DIMM, DIMM);

  k_rope<<<(64 * SEQ * 32 + 255) / 256, 256, 0, stream>>>(Qh, Kh, cosT, sinT);

  k_attn<<<dim3(NP, 64), 256, 0, stream>>>(Qh, Kh, Vh, AO);

  k_gemm<1><<<dim3(DIMM / 128, MROWS / 128), 256, 0, stream>>>(
      AO, WoutT, out_b, nullptr, nullptr, nullptr, out, MROWS, DIMM, DIMM);
}

// Round 8
// 212.233 us; speedup vs baseline: 1.1855x; 1.1855x over previous
//
#include <hip/hip_runtime.h>

typedef __bf16 bf16_t;
typedef __bf16 bf16x8 __attribute__((ext_vector_type(8)));
typedef float  f32x4  __attribute__((ext_vector_type(4)));
typedef float  f32x16 __attribute__((ext_vector_type(16)));
typedef unsigned u32x4 __attribute__((ext_vector_type(4)));

#define DIMM  1024
#define NHEAD 16
#define HDIM  64
#define BATCH 4
#define SEQ   2048
#define MROWS (BATCH*SEQ)   // 8192

#define AQB   128           // q rows per attn block
#define AKV   64            // kv per tile
#define NP    (SEQ/AQB)     // 16 q-blocks
#define SKS   72            // LDS row stride (elems), 144B, 16B-aligned
#define LOG2E 1.44269504088896f

__device__ __forceinline__ void gload_lds16(const bf16_t* g, bf16_t* l) {
  __builtin_amdgcn_global_load_lds(
      (const __attribute__((address_space(1))) void*)g,
      (__attribute__((address_space(3))) void*)l, 16, 0, 0);
}

__device__ __forceinline__ unsigned short f2bu(float f) {
  bf16_t b = (bf16_t)f;
  return __builtin_bit_cast(unsigned short, b);
}
__device__ __forceinline__ float bu2f(unsigned short u) {
  return __uint_as_float(((unsigned)u) << 16);
}
__device__ __forceinline__ unsigned packbf(float a, float b) {
  return (unsigned)f2bu(a) | ((unsigned)f2bu(b) << 16);
}
__device__ __forceinline__ float fexp2(float x) {   // v_exp_f32 = 2^x
  float r; asm("v_exp_f32 %0, %1" : "=v"(r) : "v"(x)); return r;
}

// ---------------- fp32 -> bf16 flat convert (4 elems/thread) ----------------
__global__ void k_convert(const float* __restrict__ in, bf16_t* __restrict__ out, int n4) {
  int i = blockIdx.x * blockDim.x + threadIdx.x;
  if (i >= n4) return;
  float4 v = reinterpret_cast<const float4*>(in)[i];
  ushort4 o;
  o.x = f2bu(v.x); o.y = f2bu(v.y); o.z = f2bu(v.z); o.w = f2bu(v.w);
  reinterpret_cast<ushort4*>(out)[i] = o;
}

// ------------- fp32 [R][C] -> bf16 [C][R] tiled transpose-convert -----------
__global__ void k_transpose_convert(const float* __restrict__ in, bf16_t* __restrict__ out,
                                    int R, int C) {
  __shared__ float tile[32][33];
  int cb = blockIdx.x * 32, rb = blockIdx.y * 32;
  int tx = threadIdx.x, ty = threadIdx.y;
  #pragma unroll
  for (int i = 0; i < 4; ++i)
    tile[ty + i*8][tx] = in[(size_t)(rb + ty + i*8) * C + cb + tx];
  __syncthreads();
  #pragma unroll
  for (int i = 0; i < 4; ++i)
    out[(size_t)(cb + ty + i*8) * R + rb + tx] = (bf16_t)tile[tx][ty + i*8];
}

// ---------------- RoPE cos/sin table [SEQ][32], fp64 trig ------------------
__global__ void k_rope_table(float* __restrict__ cosT, float* __restrict__ sinT) {
  int id = blockIdx.x * blockDim.x + threadIdx.x;
  if (id >= SEQ * 32) return;
  int t = id >> 5, i = id & 31;
  double ang = (double)t * pow(10000.0, -(double)i / 32.0);
  cosT[id] = (float)cos(ang);
  sinT[id] = (float)sin(ang);
}

// --- RoPE in-place on Q,K; Q additionally * 0.125*log2(e) (exp2-domain) ----
__global__ void k_rope(bf16_t* __restrict__ Q, bf16_t* __restrict__ Kb,
                       const float* __restrict__ cosT, const float* __restrict__ sinT) {
  int id = blockIdx.x * blockDim.x + threadIdx.x;  // (bh*SEQ + t)*32 + i
  if (id >= 64 * SEQ * 32) return;
  int i = id & 31;
  int t = (id >> 5) & (SEQ - 1);
  float c = cosT[(t << 5) + i], s = sinT[(t << 5) + i];
  unsigned* Qu = reinterpret_cast<unsigned*>(Q);
  unsigned* Ku = reinterpret_cast<unsigned*>(Kb);
  const float qs = 0.125f * LOG2E;
  {
    unsigned u = Qu[id];
    float x1 = bu2f((unsigned short)(u & 0xffffu));
    float x2 = bu2f((unsigned short)(u >> 16));
    Qu[id] = packbf((x1 * c - x2 * s) * qs, (x2 * c + x1 * s) * qs);
  }
  {
    unsigned u = Ku[id];
    float x1 = bu2f((unsigned short)(u & 0xffffu));
    float x2 = bu2f((unsigned short)(u >> 16));
    Ku[id] = packbf(x1 * c - x2 * s, x2 * c + x1 * s);
  }
}

// --------------- bf16 GEMM C = A[M][K] * BT[N][K]^T + bias -----------------
// MODE 0: scatter to q/k/v head layout (bf16).  MODE 1: fp32 out [M][N].
template<int MODE>
__global__ __launch_bounds__(256) void k_gemm(
    const bf16_t* __restrict__ A, const bf16_t* __restrict__ BT,
    const float* __restrict__ bias,
    bf16_t* __restrict__ q, bf16_t* __restrict__ k, bf16_t* __restrict__ v,
    float* __restrict__ outf, int M, int N, int K)
{
  __shared__ bf16_t sA[128 * 32];
  __shared__ bf16_t sB[128 * 32];
  const int tid = threadIdx.x;
  const int w = tid >> 6, lane = tid & 63;
  const int wr = w >> 1, wc = w & 1;
  const int l15 = lane & 15, l4 = lane >> 4;

  // bijective XCD swizzle (grids are multiples of 8)
  int nwg = gridDim.x * gridDim.y;
  int id  = blockIdx.y * gridDim.x + blockIdx.x;
  int cpx = nwg >> 3;
  int sid = (id & 7) * cpx + (id >> 3);
  int bx = sid % gridDim.x, by = sid / gridDim.x;

  const int rowA0 = by * 128;
  const int colB0 = bx * 128;

  f32x4 acc[4][4] = {};

  const int nkt = K >> 5;
  for (int kt = 0; kt < nkt; ++kt) {
    __syncthreads();
    #pragma unroll
    for (int i = 0; i < 2; ++i) {
      int c = i * 256 + w * 64 + lane;          // chunk id, 512 per tile
      int row = c >> 2, k8 = (c & 3) * 8;
      gload_lds16(A  + (size_t)(rowA0 + row) * K + kt * 32 + k8, sA + (i * 256 + w * 64) * 8);
      gload_lds16(BT + (size_t)(colB0 + row) * K + kt * 32 + k8, sB + (i * 256 + w * 64) * 8);
    }
    asm volatile("s_waitcnt vmcnt(0)" ::: "memory");
    __syncthreads();
    bf16x8 af[4], bfr[4];
    #pragma unroll
    for (int mi = 0; mi < 4; ++mi)
      af[mi] = *reinterpret_cast<const bf16x8*>(sA + (wr * 64 + mi * 16 + l15) * 32 + l4 * 8);
    #pragma unroll
    for (int ni = 0; ni < 4; ++ni)
      bfr[ni] = *reinterpret_cast<const bf16x8*>(sB + (wc * 64 + ni * 16 + l15) * 32 + l4 * 8);
    #pragma unroll
    for (int mi = 0; mi < 4; ++mi)
      #pragma unroll
      for (int ni = 0; ni < 4; ++ni)
        acc[mi][ni] = __builtin_amdgcn_mfma_f32_16x16x32_bf16(af[mi], bfr[ni], acc[mi][ni], 0, 0, 0);
  }

  #pragma unroll
  for (int mi = 0; mi < 4; ++mi) {
    #pragma unroll
    for (int ni = 0; ni < 4; ++ni) {
      int n = colB0 + wc * 64 + ni * 16 + l15;
      float bs = bias[n];
      #pragma unroll
      for (int r = 0; r < 4; ++r) {
        int m = rowA0 + wr * 64 + mi * 16 + l4 * 4 + r;
        float val = acc[mi][ni][r] + bs;
        if (MODE == 0) {
          int which = n >> 10, hd = n & 1023;
          int h = hd >> 6, d = hd & 63;
          int b = m >> 11, t = m & 2047;
          bf16_t* dst = (which == 0) ? q : (which == 1) ? k : v;
          dst[((size_t)(b * NHEAD + h) * SEQ + t) * HDIM + d] = (bf16_t)val;
        } else {
          outf[(size_t)m * N + n] = val;
        }
      }
    }
  }
}

// ------------- causal flash attention: swapped-operand 32x32 ----------------
// 4 waves x 32 q cols each (QBLK=128), KVBLK=64, double-buffered K/V^T LDS.
// S^T = mfma(K,Q): lane owns P[*][q=lane&31] -> in-register softmax in
// exp2-domain. O^T = mfma(V^T, P). Epilogue sO aliases sK.
// GRID BALANCE (R7 lesson): XCD = id%8, CU = (id/8)%32 -> a CU hosts ids
// {r, r+256, r+512, r+768}. Assign qblk by dispatch quartile j=id>>8 with
// k=(id>>6)&3:  j0:{15,13,11,9} j1:{0,2,4,6} j2:{14,12,10,8} j3:{1,3,5,7}
// -> per-CU tile total = (32-4k)+(2+4k)+(30-4k)+(4+4k) = 68 for EVERY CU.
// R7's (16,64) grid put all same-length blocks on one XCD (2.4x imbalance).
__global__ __launch_bounds__(256, 2) void k_attn(
    const bf16_t* __restrict__ Q, const bf16_t* __restrict__ Kb,
    const bf16_t* __restrict__ Vb, bf16_t* __restrict__ O)
{
  __shared__ bf16_t sK[2][64 * SKS];
  __shared__ bf16_t sV[2][64 * SKS];   // V^T: [d][kv]

  const int tid = threadIdx.x;
  const int w = tid >> 6, lane = tid & 63;
  const int l31 = lane & 31, hi = lane >> 5;

  const int id = blockIdx.x;
  const int j4 = id >> 8;            // dispatch quartile (longest first)
  const int k4 = (id >> 6) & 3;
  const int bh = id & 63;
  const int qblk = (j4 == 0) ? 15 - 2 * k4
                 : (j4 == 1) ? 2 * k4
                 : (j4 == 2) ? 14 - 2 * k4
                 :             2 * k4 + 1;

  const size_t hbase = (size_t)bh * SEQ * HDIM;
  const int b = bh >> 4, h = bh & 15;
  const int srow = tid >> 3, sslot = tid & 7;

  const int qbase = qblk * AQB + 32 * w;
  const int nt = 2 * qblk + 2;

  // Q fragments (pre-scaled by 0.125*log2e): B-op, n=q=l31, k=kt*16+8*hi+j
  bf16x8 qf[4];
  #pragma unroll
  for (int kt = 0; kt < 4; ++kt)
    qf[kt] = *reinterpret_cast<const bf16x8*>(
        Q + hbase + (size_t)(qbase + l31) * HDIM + kt * 16 + hi * 8);
  asm volatile("s_waitcnt vmcnt(0)" ::: "memory");
  asm volatile("" : "+v"(qf[0]), "+v"(qf[1]), "+v"(qf[2]), "+v"(qf[3]));

  u32x4 kr[2], vr[2];
  auto issue = [&](int t) {
    const bf16_t* kp = Kb + hbase + (size_t)(t * AKV + srow) * HDIM + sslot * 8;
    const bf16_t* vp = Vb + hbase + (size_t)(t * AKV + srow) * HDIM + sslot * 8;
    asm volatile("global_load_dwordx4 %0, %1, off" : "=v"(kr[0]) : "v"(kp));
    asm volatile("global_load_dwordx4 %0, %1, off" : "=v"(kr[1]) : "v"(kp + 32 * HDIM));
    asm volatile("global_load_dwordx4 %0, %1, off" : "=v"(vr[0]) : "v"(vp));
    asm volatile("global_load_dwordx4 %0, %1, off" : "=v"(vr[1]) : "v"(vp + 32 * HDIM));
  };
  auto stage = [&](int nb) {
    #pragma unroll
    for (int cc = 0; cc < 2; ++cc) {
      int row = srow + 32 * cc;                  // kv row
      *reinterpret_cast<u32x4*>(&sK[nb][row * SKS + ((sslot ^ (row >> 3)) << 3)]) = kr[cc];
      bf16x8 vv = __builtin_bit_cast(bf16x8, vr[cc]);
      #pragma unroll
      for (int j = 0; j < 8; ++j) {
        int d = sslot * 8 + j;
        sV[nb][d * SKS + (((row >> 3) ^ sslot) << 3) + (row & 7)] = vv[j];
      }
    }
  };

  float mrun = -1e30f, lrun = 0.f;   // per lane: q = qbase + l31 (log2 domain)
  f32x16 accO[2] = {};               // O^T: d = 32*dt + (r&3)+8*(r>>2)+4*hi, q = l31

  // prologue
  issue(0);
  asm volatile("s_waitcnt vmcnt(0)" ::: "memory");
  stage(0);
  issue(1);
  asm volatile("s_waitcnt lgkmcnt(0)" ::: "memory");
  __builtin_amdgcn_s_barrier();
  asm volatile("" ::: "memory");

  for (int t = 0; t < nt; ++t) {
    const int c = t & 1;
    if (t + 1 < nt) {
      asm volatile("s_waitcnt vmcnt(0)" ::: "memory");
      stage(c ^ 1);
      if (t + 2 < nt) issue(t + 2);
    }
    const bool masked = (t * AKV + AKV - 1 > qbase);   // wave-uniform
    #pragma unroll
    for (int sub = 0; sub < 2; ++sub) {
      // S^T = K x Q : D[kv][q]  (log2-domain logits)
      f32x16 sc = {};
      __builtin_amdgcn_s_setprio(1);
      #pragma unroll
      for (int kt = 0; kt < 4; ++kt) {
        int krow = 32 * sub + l31;
        bf16x8 kf = *reinterpret_cast<const bf16x8*>(
            &sK[c][krow * SKS + (((2 * kt + hi) ^ (krow >> 3)) << 3)]);
        sc = __builtin_amdgcn_mfma_f32_32x32x16_bf16(kf, qf[kt], sc, 0, 0, 0);
      }
      __builtin_amdgcn_s_setprio(0);

      // in-register softmax over kv (rows in regs; q = l31 lane-local)
      float p[16];
      const int qa = qbase + l31;
      const int kb0 = t * AKV + 32 * sub + 4 * hi;
      #pragma unroll
      for (int r = 0; r < 16; ++r) {
        float s = sc[r];
        if (masked) {
          int kvi = kb0 + (r & 3) + 8 * (r >> 2);
          if (kvi > qa) s = -1e30f;
        }
        p[r] = s;
      }
      // max tree (max3-fusable)
      float m0 = fmaxf(fmaxf(p[0],  p[1]),  p[2]);
      float m1 = fmaxf(fmaxf(p[3],  p[4]),  p[5]);
      float m2 = fmaxf(fmaxf(p[6],  p[7]),  p[8]);
      float m3 = fmaxf(fmaxf(p[9],  p[10]), p[11]);
      float m4 = fmaxf(fmaxf(p[12], p[13]), p[14]);
      float mt = fmaxf(fmaxf(fmaxf(m0, m1), fmaxf(m2, m3)), fmaxf(m4, p[15]));
      mt = fmaxf(mt, __shfl_xor(mt, 32));            // cross-half max
      if (!__all(mt <= mrun + 11.54f)) {             // T13 defer-max (8*log2e)
        float mnew = fmaxf(mrun, mt);
        float scl = fexp2(mrun - mnew);
        mrun = mnew;
        lrun *= scl;
        #pragma unroll
        for (int i = 0; i < 16; ++i) { accO[0][i] *= scl; accO[1][i] *= scl; }
      }
      float rs = 0.f;
      #pragma unroll
      for (int r = 0; r < 16; ++r) { p[r] = fexp2(p[r] - mrun); rs += p[r]; }
      lrun += rs + __shfl_xor(rs, 32);

      // pack P to bf16 B-fragments; half-exchange via shfl_xor(32).
      bf16x8 pf[2];
      #pragma unroll
      for (int kt = 0; kt < 2; ++kt) {
        unsigned P01 = packbf(p[8*kt+0], p[8*kt+1]);   // rows 16kt+(0,1)+4hi
        unsigned P23 = packbf(p[8*kt+2], p[8*kt+3]);   // rows 16kt+(2,3)+4hi
        unsigned P45 = packbf(p[8*kt+4], p[8*kt+5]);   // rows 16kt+(8,9)+4hi
        unsigned P67 = packbf(p[8*kt+6], p[8*kt+7]);   // rows 16kt+(10,11)+4hi
        unsigned ra = __shfl_xor(hi == 0 ? P45 : P01, 32);
        unsigned rb = __shfl_xor(hi == 0 ? P67 : P23, 32);
        unsigned dw0 = hi == 0 ? P01 : ra;   // rows (0,1) / (8,9)
        unsigned dw1 = hi == 0 ? P23 : rb;   // rows (2,3) / (10,11)
        unsigned dw2 = hi == 0 ? ra : P45;   // rows (4,5) / (12,13)
        unsigned dw3 = hi == 0 ? rb : P67;   // rows (6,7) / (14,15)
        pf[kt] = __builtin_bit_cast(bf16x8, (u32x4){dw0, dw1, dw2, dw3});
      }

      // O^T += V^T x P : D[d][q]
      __builtin_amdgcn_s_setprio(1);
      #pragma unroll
      for (int dt = 0; dt < 2; ++dt) {
        #pragma unroll
        for (int kt = 0; kt < 2; ++kt) {
          int vrow = 32 * dt + l31;
          bf16x8 vf = *reinterpret_cast<const bf16x8*>(
              &sV[c][vrow * SKS + (((4 * sub + 2 * kt + hi) ^ (vrow >> 3)) << 3)]);
          accO[dt] = __builtin_amdgcn_mfma_f32_32x32x16_bf16(vf, pf[kt], accO[dt], 0, 0, 0);
        }
      }
      __builtin_amdgcn_s_setprio(0);
    }
    asm volatile("s_waitcnt lgkmcnt(0)" ::: "memory");
    __builtin_amdgcn_s_barrier();
    asm volatile("" ::: "memory");
  }

  // epilogue: transpose O^T -> O via per-wave LDS region aliased onto sK
  // (safe: final barrier above means all sK reads are done; per-wave region)
  bf16_t* sOw = &sK[0][0] + w * (32 * SKS);
  float inv = 1.f / lrun;
  #pragma unroll
  for (int dt = 0; dt < 2; ++dt)
    #pragma unroll
    for (int r = 0; r < 16; ++r) {
      int d = 32 * dt + (r & 3) + 8 * (r >> 2) + 4 * hi;
      sOw[l31 * SKS + (d ^ ((l31 >> 3) << 3))] = (bf16_t)(accO[dt][r] * inv);
    }
  #pragma unroll
  for (int i = 0; i < 4; ++i) {
    int qr = 8 * i + (lane >> 3);
    int ch = lane & 7;
    bf16x8 vvv = *reinterpret_cast<const bf16x8*>(
        &sOw[qr * SKS + ((ch ^ (qr >> 3)) << 3)]);
    *reinterpret_cast<bf16x8*>(
        O + ((size_t)(b * SEQ + qbase + qr)) * DIMM + h * HDIM + ch * 8) = vvv;
  }
}

// ---------------------------------------------------------------------------
extern "C" void kernel_launch(void* const* d_in, const int* in_sizes, int n_in,
                              void* d_out, int out_size, void* d_ws, size_t ws_size,
                              hipStream_t stream) {
  const float* x     = (const float*)d_in[0];
  // d_in[1] = mask (causal tril) — structure hardcoded
  const float* qkv_w = (const float*)d_in[2];
  const float* qkv_b = (const float*)d_in[3];
  const float* out_w = (const float*)d_in[4];
  const float* out_b = (const float*)d_in[5];
  float* out = (float*)d_out;

  char* ws = (char*)d_ws;
  size_t off = 0;
  auto alloc = [&](size_t bytes) {
    char* p = ws + off;
    off += (bytes + 255) & ~(size_t)255;
    return (void*)p;
  };
  bf16_t* Xb    = (bf16_t*)alloc((size_t)MROWS * DIMM * 2);
  bf16_t* WqkvT = (bf16_t*)alloc((size_t)3 * DIMM * DIMM * 2);
  bf16_t* WoutT = (bf16_t*)alloc((size_t)DIMM * DIMM * 2);
  bf16_t* Qh    = (bf16_t*)alloc((size_t)64 * SEQ * HDIM * 2);
  bf16_t* Kh    = (bf16_t*)alloc((size_t)64 * SEQ * HDIM * 2);
  bf16_t* Vh    = (bf16_t*)alloc((size_t)64 * SEQ * HDIM * 2);
  bf16_t* AO    = (bf16_t*)alloc((size_t)MROWS * DIMM * 2);
  float*  cosT  = (float*)alloc((size_t)SEQ * 32 * 4);
  float*  sinT  = (float*)alloc((size_t)SEQ * 32 * 4);

  k_convert<<<(MROWS * DIMM / 4 + 255) / 256, 256, 0, stream>>>(x, Xb, MROWS * DIMM / 4);
  k_transpose_convert<<<dim3(3 * DIMM / 32, DIMM / 32), dim3(32, 8), 0, stream>>>(qkv_w, WqkvT, DIMM, 3 * DIMM);
  k_transpose_convert<<<dim3(DIMM / 32, DIMM / 32), dim3(32, 8), 0, stream>>>(out_w, WoutT, DIMM, DIMM);
  k_rope_table<<<(SEQ * 32 + 255) / 256, 256, 0, stream>>>(cosT, sinT);

  k_gemm<0><<<dim3(3 * DIMM / 128, MROWS / 128), 256, 0, stream>>>(
      Xb, WqkvT, qkv_b, Qh, Kh, Vh, nullptr, MROWS, 3 * DIMM, DIMM);

  k_rope<<<(64 * SEQ * 32 + 255) / 256, 256, 0, stream>>>(Qh, Kh, cosT, sinT);

  k_attn<<<dim3(NP * 64), 256, 0, stream>>>(Qh, Kh, Vh, AO);

  k_gemm<1><<<dim3(DIMM / 128, MROWS / 128), 256, 0, stream>>>(
      AO, WoutT, out_b, nullptr, nullptr, nullptr, out, MROWS, DIMM, DIMM);
}

// Round 9
// 203.625 us; speedup vs baseline: 1.2356x; 1.0423x over previous
//
#include <hip/hip_runtime.h>

typedef __bf16 bf16_t;
typedef __bf16 bf16x8 __attribute__((ext_vector_type(8)));
typedef float  f32x4  __attribute__((ext_vector_type(4)));
typedef float  f32x16 __attribute__((ext_vector_type(16)));
typedef unsigned u32x4 __attribute__((ext_vector_type(4)));

#define DIMM  1024
#define NHEAD 16
#define HDIM  64
#define BATCH 4
#define SEQ   2048
#define MROWS (BATCH*SEQ)   // 8192

#define AQB   128           // q rows per attn block
#define AKV   64            // kv per tile
#define NP    (SEQ/AQB)     // 16 q-blocks
#define SKS   72            // LDS row stride (elems), 144B, 16B-aligned
#define LOG2E 1.44269504088896f

__device__ __forceinline__ void gload_lds16(const bf16_t* g, bf16_t* l) {
  __builtin_amdgcn_global_load_lds(
      (const __attribute__((address_space(1))) void*)g,
      (__attribute__((address_space(3))) void*)l, 16, 0, 0);
}

__device__ __forceinline__ unsigned short f2bu(float f) {
  bf16_t b = (bf16_t)f;
  return __builtin_bit_cast(unsigned short, b);
}
__device__ __forceinline__ float bu2f(unsigned short u) {
  return __uint_as_float(((unsigned)u) << 16);
}
__device__ __forceinline__ unsigned packbf(float a, float b) {
  return (unsigned)f2bu(a) | ((unsigned)f2bu(b) << 16);
}
__device__ __forceinline__ float fexp2(float x) {   // v_exp_f32 = 2^x
  float r; asm("v_exp_f32 %0, %1" : "=v"(r) : "v"(x)); return r;
}

// ---------------- fp32 -> bf16 flat convert (4 elems/thread) ----------------
__global__ void k_convert(const float* __restrict__ in, bf16_t* __restrict__ out, int n4) {
  int i = blockIdx.x * blockDim.x + threadIdx.x;
  if (i >= n4) return;
  float4 v = reinterpret_cast<const float4*>(in)[i];
  ushort4 o;
  o.x = f2bu(v.x); o.y = f2bu(v.y); o.z = f2bu(v.z); o.w = f2bu(v.w);
  reinterpret_cast<ushort4*>(out)[i] = o;
}

// ------------- fp32 [R][C] -> bf16 [C][R] tiled transpose-convert -----------
__global__ void k_transpose_convert(const float* __restrict__ in, bf16_t* __restrict__ out,
                                    int R, int C) {
  __shared__ float tile[32][33];
  int cb = blockIdx.x * 32, rb = blockIdx.y * 32;
  int tx = threadIdx.x, ty = threadIdx.y;
  #pragma unroll
  for (int i = 0; i < 4; ++i)
    tile[ty + i*8][tx] = in[(size_t)(rb + ty + i*8) * C + cb + tx];
  __syncthreads();
  #pragma unroll
  for (int i = 0; i < 4; ++i)
    out[(size_t)(cb + ty + i*8) * R + rb + tx] = (bf16_t)tile[tx][ty + i*8];
}

// ---------------- RoPE cos/sin table [SEQ][32], fp64 trig ------------------
__global__ void k_rope_table(float* __restrict__ cosT, float* __restrict__ sinT) {
  int id = blockIdx.x * blockDim.x + threadIdx.x;
  if (id >= SEQ * 32) return;
  int t = id >> 5, i = id & 31;
  double ang = (double)t * pow(10000.0, -(double)i / 32.0);
  cosT[id] = (float)cos(ang);
  sinT[id] = (float)sin(ang);
}

// --- RoPE in-place on Q,K; Q additionally * 0.125*log2(e) (exp2-domain) ----
__global__ void k_rope(bf16_t* __restrict__ Q, bf16_t* __restrict__ Kb,
                       const float* __restrict__ cosT, const float* __restrict__ sinT) {
  int id = blockIdx.x * blockDim.x + threadIdx.x;  // (bh*SEQ + t)*32 + i
  if (id >= 64 * SEQ * 32) return;
  int i = id & 31;
  int t = (id >> 5) & (SEQ - 1);
  float c = cosT[(t << 5) + i], s = sinT[(t << 5) + i];
  unsigned* Qu = reinterpret_cast<unsigned*>(Q);
  unsigned* Ku = reinterpret_cast<unsigned*>(Kb);
  const float qs = 0.125f * LOG2E;
  {
    unsigned u = Qu[id];
    float x1 = bu2f((unsigned short)(u & 0xffffu));
    float x2 = bu2f((unsigned short)(u >> 16));
    Qu[id] = packbf((x1 * c - x2 * s) * qs, (x2 * c + x1 * s) * qs);
  }
  {
    unsigned u = Ku[id];
    float x1 = bu2f((unsigned short)(u & 0xffffu));
    float x2 = bu2f((unsigned short)(u >> 16));
    Ku[id] = packbf(x1 * c - x2 * s, x2 * c + x1 * s);
  }
}

// ---------- 256x256 8-phase bf16 GEMM, QKV projection (M=8192 N=3072 K=1024)
// T2+T3+T4+T5 per the 8-phase template. Half-tile unit = K-half (256rows x 32k).
// Phase (ks,mh): 16 MFMA = quadrant. Staging: A.k0@ph3 B.k0@ph4 A.k1@ph5
// B.k1@ph6 (tile t+2, buf of t); next-tile halves @ph7,8 and next ph1,2.
// vmcnt(4) at ph4/ph8 forces all but the newest 2 half-tiles complete.
// LDS layout per K-half: [R=row>>1][64], elem(row,k): col=(row&1)*32+k,
// 16B slot swizz: slot' = ((row&1)*4 + k/8) ^ (R&7). Linear gload_lds dest;
// inverse swizzle applied to the GLOBAL source (both-sides rule).
__global__ __launch_bounds__(512, 2) void k_gemm0(
    const bf16_t* __restrict__ A, const bf16_t* __restrict__ BT,
    const float* __restrict__ bias,
    bf16_t* __restrict__ q, bf16_t* __restrict__ k, bf16_t* __restrict__ v)
{
  __shared__ bf16_t sA[2][2][128 * 64];   // [buf][khalf]
  __shared__ bf16_t sB[2][2][128 * 64];

  const int tid = threadIdx.x;
  const int w = tid >> 6;
  const int lane = tid & 63;
  const int wm = w >> 2, wn = w & 3;       // 2M x 4N waves
  const int l15 = lane & 15, l4 = lane >> 4;

  // bijective XCD swizzle (nwg = 384, multiple of 8)
  int nwg = gridDim.x * gridDim.y;
  int id  = blockIdx.y * gridDim.x + blockIdx.x;
  int cpx = nwg >> 3;
  int sid = (id & 7) * cpx + (id >> 3);
  int bx = sid % gridDim.x, by = sid / gridDim.x;
  const int rowA0 = by * 256, colB0 = bx * 256;

  f32x4 acc[8][4] = {};
  bf16x8 bf_[4];

  auto stage = [&](int tile, int part) {   // part: 0=A.k0 1=B.k0 2=A.k1 3=B.k1
    if (tile >= 16) return;
    const int kh = part >> 1;
    const bool isB = part & 1;
    const bf16_t* src = isB ? BT : A;
    const int r0 = isB ? colB0 : rowA0;
    bf16_t* dst = (isB ? &sB[0][0][0] : &sA[0][0][0]) + ((tile & 1) * 2 + kh) * (128 * 64);
    #pragma unroll
    for (int call = 0; call < 2; ++call) {
      int n = call * 512 + tid;
      int R = n >> 3, slot = n & 7;
      int sp = slot ^ (R & 7);
      int row = R * 2 + (sp >> 2);
      gload_lds16(src + (size_t)(r0 + row) * 1024 + tile * 64 + kh * 32 + (sp & 3) * 8,
                  dst + n * 8);
    }
  };

  auto rdA = [&](int bc, int kh, int mfa) -> bf16x8 {
    int row = wm * 128 + mfa * 16 + l15;
    int R = row >> 1;
    int slot = (((row & 1) << 2) | l4) ^ (R & 7);
    return *reinterpret_cast<const bf16x8*>(&sA[bc][kh][R * 64 + slot * 8]);
  };
  auto rdB = [&](int bc, int kh, int nf) -> bf16x8 {
    int row = wn * 64 + nf * 16 + l15;
    int R = row >> 1;
    int slot = (((row & 1) << 2) | l4) ^ (R & 7);
    return *reinterpret_cast<const bf16x8*>(&sB[bc][kh][R * 64 + slot * 8]);
  };

  auto phase = [&](int bc, int kh, int mh, int stile, int spart, int wait_n) {
    bf16x8 af[4];
    if (mh == 0) {
      #pragma unroll
      for (int nf = 0; nf < 4; ++nf) bf_[nf] = rdB(bc, kh, nf);
    }
    #pragma unroll
    for (int mf = 0; mf < 4; ++mf) af[mf] = rdA(bc, kh, mh * 4 + mf);
    stage(stile, spart);
    if (wait_n == 4)      asm volatile("s_waitcnt vmcnt(4)" ::: "memory");
    else if (wait_n == 0) asm volatile("s_waitcnt vmcnt(0)" ::: "memory");
    __builtin_amdgcn_s_barrier();
    __builtin_amdgcn_s_setprio(1);
    #pragma unroll
    for (int mf = 0; mf < 4; ++mf)
      #pragma unroll
      for (int nf = 0; nf < 4; ++nf)
        acc[mh * 4 + mf][nf] = __builtin_amdgcn_mfma_f32_16x16x32_bf16(
            af[mf], bf_[nf], acc[mh * 4 + mf][nf], 0, 0, 0);
    __builtin_amdgcn_s_setprio(0);
    __builtin_amdgcn_s_barrier();
  };

  // prologue: tile0 fully + tile1 k0-halves; wait all but newest 2 half-tiles
  stage(0, 0); stage(0, 1); stage(0, 2); stage(0, 3);
  stage(1, 0); stage(1, 1);
  asm volatile("s_waitcnt vmcnt(4)" ::: "memory");
  __builtin_amdgcn_s_barrier();

  for (int i = 0; i < 8; ++i) {
    const int t0 = 2 * i, t1 = 2 * i + 1;
    phase(0, 0, 0, t1,     2, -1);                    // ph1  stage A.k1[2i+1]
    phase(0, 0, 1, t1,     3, -1);                    // ph2  stage B.k1[2i+1]
    phase(0, 1, 0, t0 + 2, 0, -1);                    // ph3  stage A.k0[2i+2]
    phase(0, 1, 1, t0 + 2, 1, (t0 + 2 < 16) ? 4 : 0); // ph4  wait
    phase(1, 0, 0, t0 + 2, 2, -1);                    // ph5  stage A.k1[2i+2]
    phase(1, 0, 1, t0 + 2, 3, -1);                    // ph6  stage B.k1[2i+2]
    phase(1, 1, 0, t0 + 3, 0, -1);                    // ph7  stage A.k0[2i+3]
    phase(1, 1, 1, t0 + 3, 1, (t0 + 3 < 16) ? 4 : 0); // ph8  wait
  }

  // epilogue: scatter to q/k/v head layout with bias
  #pragma unroll
  for (int mfa = 0; mfa < 8; ++mfa) {
    #pragma unroll
    for (int nf = 0; nf < 4; ++nf) {
      int n = colB0 + wn * 64 + nf * 16 + l15;
      float bs = bias[n];
      int which = n >> 10, hd = n & 1023;
      int h = hd >> 6, d = hd & 63;
      bf16_t* dst = (which == 0) ? q : (which == 1) ? k : v;
      #pragma unroll
      for (int r = 0; r < 4; ++r) {
        int m = rowA0 + wm * 128 + mfa * 16 + l4 * 4 + r;
        int b = m >> 11, t = m & 2047;
        dst[((size_t)(b * NHEAD + h) * SEQ + t) * HDIM + d] = (bf16_t)(acc[mfa][nf][r] + bs);
      }
    }
  }
}

// --------------- 128x128 bf16 GEMM (out-proj): fp32 out [M][N] -------------
__global__ __launch_bounds__(256) void k_gemm1(
    const bf16_t* __restrict__ A, const bf16_t* __restrict__ BT,
    const float* __restrict__ bias, float* __restrict__ outf, int M, int N, int K)
{
  __shared__ bf16_t sA[128 * 32];
  __shared__ bf16_t sB[128 * 32];
  const int tid = threadIdx.x;
  const int w = tid >> 6, lane = tid & 63;
  const int wr = w >> 1, wc = w & 1;
  const int l15 = lane & 15, l4 = lane >> 4;

  int nwg = gridDim.x * gridDim.y;
  int id  = blockIdx.y * gridDim.x + blockIdx.x;
  int cpx = nwg >> 3;
  int sid = (id & 7) * cpx + (id >> 3);
  int bx = sid % gridDim.x, by = sid / gridDim.x;

  const int rowA0 = by * 128;
  const int colB0 = bx * 128;

  f32x4 acc[4][4] = {};

  const int nkt = K >> 5;
  for (int kt = 0; kt < nkt; ++kt) {
    __syncthreads();
    #pragma unroll
    for (int i = 0; i < 2; ++i) {
      int c = i * 256 + w * 64 + lane;
      int row = c >> 2, k8 = (c & 3) * 8;
      gload_lds16(A  + (size_t)(rowA0 + row) * K + kt * 32 + k8, sA + (i * 256 + w * 64) * 8);
      gload_lds16(BT + (size_t)(colB0 + row) * K + kt * 32 + k8, sB + (i * 256 + w * 64) * 8);
    }
    asm volatile("s_waitcnt vmcnt(0)" ::: "memory");
    __syncthreads();
    bf16x8 af[4], bfr[4];
    #pragma unroll
    for (int mi = 0; mi < 4; ++mi)
      af[mi] = *reinterpret_cast<const bf16x8*>(sA + (wr * 64 + mi * 16 + l15) * 32 + l4 * 8);
    #pragma unroll
    for (int ni = 0; ni < 4; ++ni)
      bfr[ni] = *reinterpret_cast<const bf16x8*>(sB + (wc * 64 + ni * 16 + l15) * 32 + l4 * 8);
    #pragma unroll
    for (int mi = 0; mi < 4; ++mi)
      #pragma unroll
      for (int ni = 0; ni < 4; ++ni)
        acc[mi][ni] = __builtin_amdgcn_mfma_f32_16x16x32_bf16(af[mi], bfr[ni], acc[mi][ni], 0, 0, 0);
  }

  #pragma unroll
  for (int mi = 0; mi < 4; ++mi) {
    #pragma unroll
    for (int ni = 0; ni < 4; ++ni) {
      int n = colB0 + wc * 64 + ni * 16 + l15;
      float bs = bias[n];
      #pragma unroll
      for (int r = 0; r < 4; ++r) {
        int m = rowA0 + wr * 64 + mi * 16 + l4 * 4 + r;
        outf[(size_t)m * N + n] = acc[mi][ni][r] + bs;
      }
    }
  }
}

// ------------- causal flash attention: swapped-operand 32x32 ----------------
// (unchanged from R8 — 89.9us, balanced quartile dispatch)
__global__ __launch_bounds__(256, 2) void k_attn(
    const bf16_t* __restrict__ Q, const bf16_t* __restrict__ Kb,
    const bf16_t* __restrict__ Vb, bf16_t* __restrict__ O)
{
  __shared__ bf16_t sK[2][64 * SKS];
  __shared__ bf16_t sV[2][64 * SKS];   // V^T: [d][kv]

  const int tid = threadIdx.x;
  const int w = tid >> 6, lane = tid & 63;
  const int l31 = lane & 31, hi = lane >> 5;

  const int id = blockIdx.x;
  const int j4 = id >> 8;            // dispatch quartile (longest first)
  const int k4 = (id >> 6) & 3;
  const int bh = id & 63;
  const int qblk = (j4 == 0) ? 15 - 2 * k4
                 : (j4 == 1) ? 2 * k4
                 : (j4 == 2) ? 14 - 2 * k4
                 :             2 * k4 + 1;

  const size_t hbase = (size_t)bh * SEQ * HDIM;
  const int b = bh >> 4, h = bh & 15;
  const int srow = tid >> 3, sslot = tid & 7;

  const int qbase = qblk * AQB + 32 * w;
  const int nt = 2 * qblk + 2;

  bf16x8 qf[4];
  #pragma unroll
  for (int kt = 0; kt < 4; ++kt)
    qf[kt] = *reinterpret_cast<const bf16x8*>(
        Q + hbase + (size_t)(qbase + l31) * HDIM + kt * 16 + hi * 8);
  asm volatile("s_waitcnt vmcnt(0)" ::: "memory");
  asm volatile("" : "+v"(qf[0]), "+v"(qf[1]), "+v"(qf[2]), "+v"(qf[3]));

  u32x4 kr[2], vr[2];
  auto issue = [&](int t) {
    const bf16_t* kp = Kb + hbase + (size_t)(t * AKV + srow) * HDIM + sslot * 8;
    const bf16_t* vp = Vb + hbase + (size_t)(t * AKV + srow) * HDIM + sslot * 8;
    asm volatile("global_load_dwordx4 %0, %1, off" : "=v"(kr[0]) : "v"(kp));
    asm volatile("global_load_dwordx4 %0, %1, off" : "=v"(kr[1]) : "v"(kp + 32 * HDIM));
    asm volatile("global_load_dwordx4 %0, %1, off" : "=v"(vr[0]) : "v"(vp));
    asm volatile("global_load_dwordx4 %0, %1, off" : "=v"(vr[1]) : "v"(vp + 32 * HDIM));
  };
  auto stage = [&](int nb) {
    #pragma unroll
    for (int cc = 0; cc < 2; ++cc) {
      int row = srow + 32 * cc;
      *reinterpret_cast<u32x4*>(&sK[nb][row * SKS + ((sslot ^ (row >> 3)) << 3)]) = kr[cc];
      bf16x8 vv = __builtin_bit_cast(bf16x8, vr[cc]);
      #pragma unroll
      for (int j = 0; j < 8; ++j) {
        int d = sslot * 8 + j;
        sV[nb][d * SKS + (((row >> 3) ^ sslot) << 3) + (row & 7)] = vv[j];
      }
    }
  };

  float mrun = -1e30f, lrun = 0.f;
  f32x16 accO[2] = {};

  issue(0);
  asm volatile("s_waitcnt vmcnt(0)" ::: "memory");
  stage(0);
  issue(1);
  asm volatile("s_waitcnt lgkmcnt(0)" ::: "memory");
  __builtin_amdgcn_s_barrier();
  asm volatile("" ::: "memory");

  for (int t = 0; t < nt; ++t) {
    const int c = t & 1;
    if (t + 1 < nt) {
      asm volatile("s_waitcnt vmcnt(0)" ::: "memory");
      stage(c ^ 1);
      if (t + 2 < nt) issue(t + 2);
    }
    const bool masked = (t * AKV + AKV - 1 > qbase);
    #pragma unroll
    for (int sub = 0; sub < 2; ++sub) {
      f32x16 sc = {};
      __builtin_amdgcn_s_setprio(1);
      #pragma unroll
      for (int kt = 0; kt < 4; ++kt) {
        int krow = 32 * sub + l31;
        bf16x8 kf = *reinterpret_cast<const bf16x8*>(
            &sK[c][krow * SKS + (((2 * kt + hi) ^ (krow >> 3)) << 3)]);
        sc = __builtin_amdgcn_mfma_f32_32x32x16_bf16(kf, qf[kt], sc, 0, 0, 0);
      }
      __builtin_amdgcn_s_setprio(0);

      float p[16];
      const int qa = qbase + l31;
      const int kb0 = t * AKV + 32 * sub + 4 * hi;
      #pragma unroll
      for (int r = 0; r < 16; ++r) {
        float s = sc[r];
        if (masked) {
          int kvi = kb0 + (r & 3) + 8 * (r >> 2);
          if (kvi > qa) s = -1e30f;
        }
        p[r] = s;
      }
      float m0 = fmaxf(fmaxf(p[0],  p[1]),  p[2]);
      float m1 = fmaxf(fmaxf(p[3],  p[4]),  p[5]);
      float m2 = fmaxf(fmaxf(p[6],  p[7]),  p[8]);
      float m3 = fmaxf(fmaxf(p[9],  p[10]), p[11]);
      float m4 = fmaxf(fmaxf(p[12], p[13]), p[14]);
      float mt = fmaxf(fmaxf(fmaxf(m0, m1), fmaxf(m2, m3)), fmaxf(m4, p[15]));
      mt = fmaxf(mt, __shfl_xor(mt, 32));
      if (!__all(mt <= mrun + 11.54f)) {
        float mnew = fmaxf(mrun, mt);
        float scl = fexp2(mrun - mnew);
        mrun = mnew;
        lrun *= scl;
        #pragma unroll
        for (int i = 0; i < 16; ++i) { accO[0][i] *= scl; accO[1][i] *= scl; }
      }
      float rs = 0.f;
      #pragma unroll
      for (int r = 0; r < 16; ++r) { p[r] = fexp2(p[r] - mrun); rs += p[r]; }
      lrun += rs + __shfl_xor(rs, 32);

      bf16x8 pf[2];
      #pragma unroll
      for (int kt = 0; kt < 2; ++kt) {
        unsigned P01 = packbf(p[8*kt+0], p[8*kt+1]);
        unsigned P23 = packbf(p[8*kt+2], p[8*kt+3]);
        unsigned P45 = packbf(p[8*kt+4], p[8*kt+5]);
        unsigned P67 = packbf(p[8*kt+6], p[8*kt+7]);
        unsigned ra = __shfl_xor(hi == 0 ? P45 : P01, 32);
        unsigned rb = __shfl_xor(hi == 0 ? P67 : P23, 32);
        unsigned dw0 = hi == 0 ? P01 : ra;
        unsigned dw1 = hi == 0 ? P23 : rb;
        unsigned dw2 = hi == 0 ? ra : P45;
        unsigned dw3 = hi == 0 ? rb : P67;
        pf[kt] = __builtin_bit_cast(bf16x8, (u32x4){dw0, dw1, dw2, dw3});
      }

      __builtin_amdgcn_s_setprio(1);
      #pragma unroll
      for (int dt = 0; dt < 2; ++dt) {
        #pragma unroll
        for (int kt = 0; kt < 2; ++kt) {
          int vrow = 32 * dt + l31;
          bf16x8 vf = *reinterpret_cast<const bf16x8*>(
              &sV[c][vrow * SKS + (((4 * sub + 2 * kt + hi) ^ (vrow >> 3)) << 3)]);
          accO[dt] = __builtin_amdgcn_mfma_f32_32x32x16_bf16(vf, pf[kt], accO[dt], 0, 0, 0);
        }
      }
      __builtin_amdgcn_s_setprio(0);
    }
    asm volatile("s_waitcnt lgkmcnt(0)" ::: "memory");
    __builtin_amdgcn_s_barrier();
    asm volatile("" ::: "memory");
  }

  bf16_t* sOw = &sK[0][0] + w * (32 * SKS);
  float inv = 1.f / lrun;
  #pragma unroll
  for (int dt = 0; dt < 2; ++dt)
    #pragma unroll
    for (int r = 0; r < 16; ++r) {
      int d = 32 * dt + (r & 3) + 8 * (r >> 2) + 4 * hi;
      sOw[l31 * SKS + (d ^ ((l31 >> 3) << 3))] = (bf16_t)(accO[dt][r] * inv);
    }
  #pragma unroll
  for (int i = 0; i < 4; ++i) {
    int qr = 8 * i + (lane >> 3);
    int ch = lane & 7;
    bf16x8 vvv = *reinterpret_cast<const bf16x8*>(
        &sOw[qr * SKS + ((ch ^ (qr >> 3)) << 3)]);
    *reinterpret_cast<bf16x8*>(
        O + ((size_t)(b * SEQ + qbase + qr)) * DIMM + h * HDIM + ch * 8) = vvv;
  }
}

// ---------------------------------------------------------------------------
extern "C" void kernel_launch(void* const* d_in, const int* in_sizes, int n_in,
                              void* d_out, int out_size, void* d_ws, size_t ws_size,
                              hipStream_t stream) {
  const float* x     = (const float*)d_in[0];
  // d_in[1] = mask (causal tril) — structure hardcoded
  const float* qkv_w = (const float*)d_in[2];
  const float* qkv_b = (const float*)d_in[3];
  const float* out_w = (const float*)d_in[4];
  const float* out_b = (const float*)d_in[5];
  float* out = (float*)d_out;

  char* ws = (char*)d_ws;
  size_t off = 0;
  auto alloc = [&](size_t bytes) {
    char* p = ws + off;
    off += (bytes + 255) & ~(size_t)255;
    return (void*)p;
  };
  bf16_t* Xb    = (bf16_t*)alloc((size_t)MROWS * DIMM * 2);
  bf16_t* WqkvT = (bf16_t*)alloc((size_t)3 * DIMM * DIMM * 2);
  bf16_t* WoutT = (bf16_t*)alloc((size_t)DIMM * DIMM * 2);
  bf16_t* Qh    = (bf16_t*)alloc((size_t)64 * SEQ * HDIM * 2);
  bf16_t* Kh    = (bf16_t*)alloc((size_t)64 * SEQ * HDIM * 2);
  bf16_t* Vh    = (bf16_t*)alloc((size_t)64 * SEQ * HDIM * 2);
  bf16_t* AO    = (bf16_t*)alloc((size_t)MROWS * DIMM * 2);
  float*  cosT  = (float*)alloc((size_t)SEQ * 32 * 4);
  float*  sinT  = (float*)alloc((size_t)SEQ * 32 * 4);

  k_convert<<<(MROWS * DIMM / 4 + 255) / 256, 256, 0, stream>>>(x, Xb, MROWS * DIMM / 4);
  k_transpose_convert<<<dim3(3 * DIMM / 32, DIMM / 32), dim3(32, 8), 0, stream>>>(qkv_w, WqkvT, DIMM, 3 * DIMM);
  k_transpose_convert<<<dim3(DIMM / 32, DIMM / 32), dim3(32, 8), 0, stream>>>(out_w, WoutT, DIMM, DIMM);
  k_rope_table<<<(SEQ * 32 + 255) / 256, 256, 0, stream>>>(cosT, sinT);

  k_gemm0<<<dim3(3 * DIMM / 256, MROWS / 256), 512, 0, stream>>>(
      Xb, WqkvT, qkv_b, Qh, Kh, Vh);

  k_rope<<<(64 * SEQ * 32 + 255) / 256, 256, 0, stream>>>(Qh, Kh, cosT, sinT);

  k_attn<<<dim3(NP * 64), 256, 0, stream>>>(Qh, Kh, Vh, AO);

  k_gemm1<<<dim3(DIMM / 128, MROWS / 128), 256, 0, stream>>>(
      AO, WoutT, out_b, out, MROWS, DIMM, DIMM);
}

// Round 11
// 195.557 us; speedup vs baseline: 1.2866x; 1.0413x over previous
//
#include <hip/hip_runtime.h>

typedef __bf16 bf16_t;
typedef __bf16 bf16x8 __attribute__((ext_vector_type(8)));
typedef float  f32x4  __attribute__((ext_vector_type(4)));
typedef float  f32x16 __attribute__((ext_vector_type(16)));
typedef unsigned u32x4 __attribute__((ext_vector_type(4)));

#define DIMM  1024
#define NHEAD 16
#define HDIM  64
#define BATCH 4
#define SEQ   2048
#define MROWS (BATCH*SEQ)   // 8192

#define AQB   128           // q rows per attn block
#define AKV   64            // kv per tile
#define NP    (SEQ/AQB)     // 16 q-blocks
#define SKS   72            // LDS row stride (elems), 144B, 16B-aligned
#define LOG2E 1.44269504088896f

__device__ __forceinline__ void gload_lds16(const bf16_t* g, bf16_t* l) {
  __builtin_amdgcn_global_load_lds(
      (const __attribute__((address_space(1))) void*)g,
      (__attribute__((address_space(3))) void*)l, 16, 0, 0);
}

__device__ __forceinline__ unsigned short f2bu(float f) {
  bf16_t b = (bf16_t)f;
  return __builtin_bit_cast(unsigned short, b);
}
__device__ __forceinline__ float bu2f(unsigned short u) {
  return __uint_as_float(((unsigned)u) << 16);
}
__device__ __forceinline__ unsigned packbf(float a, float b) {
  return (unsigned)f2bu(a) | ((unsigned)f2bu(b) << 16);
}
__device__ __forceinline__ float fexp2(float x) {   // v_exp_f32 = 2^x
  float r; asm("v_exp_f32 %0, %1" : "=v"(r) : "v"(x)); return r;
}

// ---------------- fp32 -> bf16 flat convert (4 elems/thread) ----------------
__global__ void k_convert(const float* __restrict__ in, bf16_t* __restrict__ out, int n4) {
  int i = blockIdx.x * blockDim.x + threadIdx.x;
  if (i >= n4) return;
  float4 v = reinterpret_cast<const float4*>(in)[i];
  ushort4 o;
  o.x = f2bu(v.x); o.y = f2bu(v.y); o.z = f2bu(v.z); o.w = f2bu(v.w);
  reinterpret_cast<ushort4*>(out)[i] = o;
}

// ------------- fp32 [R][C] -> bf16 [C][R] tiled transpose-convert -----------
__global__ void k_transpose_convert(const float* __restrict__ in, bf16_t* __restrict__ out,
                                    int R, int C) {
  __shared__ float tile[32][33];
  int cb = blockIdx.x * 32, rb = blockIdx.y * 32;
  int tx = threadIdx.x, ty = threadIdx.y;
  #pragma unroll
  for (int i = 0; i < 4; ++i)
    tile[ty + i*8][tx] = in[(size_t)(rb + ty + i*8) * C + cb + tx];
  __syncthreads();
  #pragma unroll
  for (int i = 0; i < 4; ++i)
    out[(size_t)(cb + ty + i*8) * R + rb + tx] = (bf16_t)tile[tx][ty + i*8];
}

// ---------------- RoPE cos/sin table [SEQ][32], fp64 trig ------------------
__global__ void k_rope_table(float* __restrict__ cosT, float* __restrict__ sinT) {
  int id = blockIdx.x * blockDim.x + threadIdx.x;
  if (id >= SEQ * 32) return;
  int t = id >> 5, i = id & 31;
  double ang = (double)t * pow(10000.0, -(double)i / 32.0);
  cosT[id] = (float)cos(ang);
  sinT[id] = (float)sin(ang);
}

// ---------- 256x256 8-phase bf16 GEMM, QKV projection (M=8192 N=3072 K=1024)
// 8-phase T2+T3+T4+T5 schedule (see R9). Epilogue is layout-aware:
//   bx<4 : Q -> rope + 0.125*log2e scale -> head layout [bh][t][d]
//   bx<8 : K -> rope -> head layout
//   else : V -> TRANSPOSED [bh][d][t], ushort4-packed stores (feeds attn's
//           vectorized V^T staging; kills the 16x ds_write_b16 scatter).
// Rope pair exchange = __shfl_xor(val,1) (adjacent-lane DPP); bias pre-rope.
__global__ __launch_bounds__(512, 2) void k_gemm0(
    const bf16_t* __restrict__ A, const bf16_t* __restrict__ BT,
    const float* __restrict__ bias,
    bf16_t* __restrict__ q, bf16_t* __restrict__ k, bf16_t* __restrict__ vt,
    const float* __restrict__ cosT, const float* __restrict__ sinT)
{
  __shared__ bf16_t sA[2][2][128 * 64];   // [buf][khalf]
  __shared__ bf16_t sB[2][2][128 * 64];

  const int tid = threadIdx.x;
  const int w = tid >> 6;
  const int lane = tid & 63;
  const int wm = w >> 2, wn = w & 3;       // 2M x 4N waves
  const int l15 = lane & 15, l4 = lane >> 4;

  // bijective XCD swizzle (nwg = 384, multiple of 8)
  int nwg = gridDim.x * gridDim.y;
  int id  = blockIdx.y * gridDim.x + blockIdx.x;
  int cpx = nwg >> 3;
  int sid = (id & 7) * cpx + (id >> 3);
  int bx = sid % gridDim.x, by = sid / gridDim.x;
  const int rowA0 = by * 256, colB0 = bx * 256;

  f32x4 acc[8][4] = {};
  bf16x8 bf_[4];

  auto stage = [&](int tile, int part) {   // part: 0=A.k0 1=B.k0 2=A.k1 3=B.k1
    if (tile >= 16) return;
    const int kh = part >> 1;
    const bool isB = part & 1;
    const bf16_t* src = isB ? BT : A;
    const int r0 = isB ? colB0 : rowA0;
    bf16_t* dst = (isB ? &sB[0][0][0] : &sA[0][0][0]) + ((tile & 1) * 2 + kh) * (128 * 64);
    #pragma unroll
    for (int call = 0; call < 2; ++call) {
      int n = call * 512 + tid;
      int R = n >> 3, slot = n & 7;
      int sp = slot ^ (R & 7);
      int row = R * 2 + (sp >> 2);
      gload_lds16(src + (size_t)(r0 + row) * 1024 + tile * 64 + kh * 32 + (sp & 3) * 8,
                  dst + n * 8);
    }
  };

  auto rdA = [&](int bc, int kh, int mfa) -> bf16x8 {
    int row = wm * 128 + mfa * 16 + l15;
    int R = row >> 1;
    int slot = (((row & 1) << 2) | l4) ^ (R & 7);
    return *reinterpret_cast<const bf16x8*>(&sA[bc][kh][R * 64 + slot * 8]);
  };
  auto rdB = [&](int bc, int kh, int nf) -> bf16x8 {
    int row = wn * 64 + nf * 16 + l15;
    int R = row >> 1;
    int slot = (((row & 1) << 2) | l4) ^ (R & 7);
    return *reinterpret_cast<const bf16x8*>(&sB[bc][kh][R * 64 + slot * 8]);
  };

  auto phase = [&](int bc, int kh, int mh, int stile, int spart, int wait_n) {
    bf16x8 af[4];
    if (mh == 0) {
      #pragma unroll
      for (int nf = 0; nf < 4; ++nf) bf_[nf] = rdB(bc, kh, nf);
    }
    #pragma unroll
    for (int mf = 0; mf < 4; ++mf) af[mf] = rdA(bc, kh, mh * 4 + mf);
    stage(stile, spart);
    if (wait_n == 4)      asm volatile("s_waitcnt vmcnt(4)" ::: "memory");
    else if (wait_n == 0) asm volatile("s_waitcnt vmcnt(0)" ::: "memory");
    __builtin_amdgcn_s_barrier();
    __builtin_amdgcn_s_setprio(1);
    #pragma unroll
    for (int mf = 0; mf < 4; ++mf)
      #pragma unroll
      for (int nf = 0; nf < 4; ++nf)
        acc[mh * 4 + mf][nf] = __builtin_amdgcn_mfma_f32_16x16x32_bf16(
            af[mf], bf_[nf], acc[mh * 4 + mf][nf], 0, 0, 0);
    __builtin_amdgcn_s_setprio(0);
    __builtin_amdgcn_s_barrier();
  };

  // prologue: tile0 fully + tile1 k0-halves; wait all but newest 2 half-tiles
  stage(0, 0); stage(0, 1); stage(0, 2); stage(0, 3);
  stage(1, 0); stage(1, 1);
  asm volatile("s_waitcnt vmcnt(4)" ::: "memory");
  __builtin_amdgcn_s_barrier();

  for (int i = 0; i < 8; ++i) {
    const int t0 = 2 * i, t1 = 2 * i + 1;
    phase(0, 0, 0, t1,     2, -1);
    phase(0, 0, 1, t1,     3, -1);
    phase(0, 1, 0, t0 + 2, 0, -1);
    phase(0, 1, 1, t0 + 2, 1, (t0 + 2 < 16) ? 4 : 0);
    phase(1, 0, 0, t0 + 2, 2, -1);
    phase(1, 0, 1, t0 + 2, 3, -1);
    phase(1, 1, 0, t0 + 3, 0, -1);
    phase(1, 1, 1, t0 + 3, 1, (t0 + 3 < 16) ? 4 : 0);
  }

  // ---- epilogue ----
  const bool isV = (bx >= 8);
  const bool isQ = (bx < 4);
  const float qs = 0.125f * LOG2E;
  if (isV) {
    #pragma unroll
    for (int mfa = 0; mfa < 8; ++mfa) {
      #pragma unroll
      for (int nf = 0; nf < 4; ++nf) {
        int n = colB0 + wn * 64 + nf * 16 + l15;
        int h = (n >> 6) & 15, d = n & 63;
        float bs = bias[n];
        int m0 = rowA0 + wm * 128 + mfa * 16 + l4 * 4;
        int b = m0 >> 11, t = m0 & 2047;
        ushort4 pk;
        pk.x = f2bu(acc[mfa][nf][0] + bs);
        pk.y = f2bu(acc[mfa][nf][1] + bs);
        pk.z = f2bu(acc[mfa][nf][2] + bs);
        pk.w = f2bu(acc[mfa][nf][3] + bs);
        *reinterpret_cast<ushort4*>(
            vt + ((size_t)((b * NHEAD + h) * HDIM + d)) * SEQ + t) = pk;
      }
    }
  } else {
    bf16_t* dst = isQ ? q : k;
    #pragma unroll
    for (int mfa = 0; mfa < 8; ++mfa) {
      #pragma unroll
      for (int nf = 0; nf < 4; ++nf) {
        int n = colB0 + wn * 64 + nf * 16 + l15;
        int h = (n >> 6) & 15, d = n & 63;
        int i2 = d >> 1;
        float bs = bias[n];
        #pragma unroll
        for (int r = 0; r < 4; ++r) {
          int m = rowA0 + wm * 128 + mfa * 16 + l4 * 4 + r;
          int b = m >> 11, t = m & 2047;
          float val = acc[mfa][nf][r] + bs;
          float prt = __shfl_xor(val, 1);    // partner within the rope pair
          float c = cosT[(t << 5) + i2], s = sinT[(t << 5) + i2];
          float y = (d & 1) ? (val * c + prt * s) : (val * c - prt * s);
          if (isQ) y *= qs;                  // exp2-domain softmax scale
          dst[((size_t)(b * NHEAD + h) * SEQ + t) * HDIM + d] = (bf16_t)y;
        }
      }
    }
  }
}

// --------------- 128x128 bf16 GEMM (out-proj): fp32 out [M][N] -------------
__global__ __launch_bounds__(256) void k_gemm1(
    const bf16_t* __restrict__ A, const bf16_t* __restrict__ BT,
    const float* __restrict__ bias, float* __restrict__ outf, int M, int N, int K)
{
  __shared__ bf16_t sA[128 * 32];
  __shared__ bf16_t sB[128 * 32];
  const int tid = threadIdx.x;
  const int w = tid >> 6, lane = tid & 63;
  const int wr = w >> 1, wc = w & 1;
  const int l15 = lane & 15, l4 = lane >> 4;

  int nwg = gridDim.x * gridDim.y;
  int id  = blockIdx.y * gridDim.x + blockIdx.x;
  int cpx = nwg >> 3;
  int sid = (id & 7) * cpx + (id >> 3);
  int bx = sid % gridDim.x, by = sid / gridDim.x;

  const int rowA0 = by * 128;
  const int colB0 = bx * 128;

  f32x4 acc[4][4] = {};

  const int nkt = K >> 5;
  for (int kt = 0; kt < nkt; ++kt) {
    __syncthreads();
    #pragma unroll
    for (int i = 0; i < 2; ++i) {
      int c = i * 256 + w * 64 + lane;
      int row = c >> 2, k8 = (c & 3) * 8;
      gload_lds16(A  + (size_t)(rowA0 + row) * K + kt * 32 + k8, sA + (i * 256 + w * 64) * 8);
      gload_lds16(BT + (size_t)(colB0 + row) * K + kt * 32 + k8, sB + (i * 256 + w * 64) * 8);
    }
    asm volatile("s_waitcnt vmcnt(0)" ::: "memory");
    __syncthreads();
    bf16x8 af[4], bfr[4];
    #pragma unroll
    for (int mi = 0; mi < 4; ++mi)
      af[mi] = *reinterpret_cast<const bf16x8*>(sA + (wr * 64 + mi * 16 + l15) * 32 + l4 * 8);
    #pragma unroll
    for (int ni = 0; ni < 4; ++ni)
      bfr[ni] = *reinterpret_cast<const bf16x8*>(sB + (wc * 64 + ni * 16 + l15) * 32 + l4 * 8);
    #pragma unroll
    for (int mi = 0; mi < 4; ++mi)
      #pragma unroll
      for (int ni = 0; ni < 4; ++ni)
        acc[mi][ni] = __builtin_amdgcn_mfma_f32_16x16x32_bf16(af[mi], bfr[ni], acc[mi][ni], 0, 0, 0);
  }

  #pragma unroll
  for (int mi = 0; mi < 4; ++mi) {
    #pragma unroll
    for (int ni = 0; ni < 4; ++ni) {
      int n = colB0 + wc * 64 + ni * 16 + l15;
      float bs = bias[n];
      #pragma unroll
      for (int r = 0; r < 4; ++r) {
        int m = rowA0 + wr * 64 + mi * 16 + l4 * 4 + r;
        outf[(size_t)m * N + n] = acc[mi][ni][r] + bs;
      }
    }
  }
}

// ------------- causal flash attention: swapped-operand 32x32 ----------------
// As R9 (balanced quartile dispatch) but V arrives PRE-TRANSPOSED from gemm0
// ([bh][d][t]) -> V^T staging is now identical to K staging (vectorized
// ds_write_b128, same swizzle); the 16x scalar-scatter transpose is gone.
// PV read path byte-identical to R9.
__global__ __launch_bounds__(256, 2) void k_attn(
    const bf16_t* __restrict__ Q, const bf16_t* __restrict__ Kb,
    const bf16_t* __restrict__ Vt, bf16_t* __restrict__ O)
{
  __shared__ bf16_t sK[2][64 * SKS];
  __shared__ bf16_t sV[2][64 * SKS];   // V^T: [d][kv]

  const int tid = threadIdx.x;
  const int w = tid >> 6, lane = tid & 63;
  const int l31 = lane & 31, hi = lane >> 5;

  const int id = blockIdx.x;
  const int j4 = id >> 8;            // dispatch quartile (longest first)
  const int k4 = (id >> 6) & 3;
  const int bh = id & 63;
  const int qblk = (j4 == 0) ? 15 - 2 * k4
                 : (j4 == 1) ? 2 * k4
                 : (j4 == 2) ? 14 - 2 * k4
                 :             2 * k4 + 1;

  const size_t hbase = (size_t)bh * SEQ * HDIM;
  const int b = bh >> 4, h = bh & 15;
  const int srow = tid >> 3, sslot = tid & 7;

  const int qbase = qblk * AQB + 32 * w;
  const int nt = 2 * qblk + 2;

  bf16x8 qf[4];
  #pragma unroll
  for (int kt = 0; kt < 4; ++kt)
    qf[kt] = *reinterpret_cast<const bf16x8*>(
        Q + hbase + (size_t)(qbase + l31) * HDIM + kt * 16 + hi * 8);
  asm volatile("s_waitcnt vmcnt(0)" ::: "memory");
  asm volatile("" : "+v"(qf[0]), "+v"(qf[1]), "+v"(qf[2]), "+v"(qf[3]));

  u32x4 kr[2], vr[2];
  auto issue = [&](int t) {
    const bf16_t* kp = Kb + hbase + (size_t)(t * AKV + srow) * HDIM + sslot * 8;
    const bf16_t* vp = Vt + hbase + (size_t)srow * SEQ + t * AKV + sslot * 8;
    asm volatile("global_load_dwordx4 %0, %1, off" : "=v"(kr[0]) : "v"(kp));
    asm volatile("global_load_dwordx4 %0, %1, off" : "=v"(kr[1]) : "v"(kp + 32 * HDIM));
    asm volatile("global_load_dwordx4 %0, %1, off" : "=v"(vr[0]) : "v"(vp));
    asm volatile("global_load_dwordx4 %0, %1, off" : "=v"(vr[1]) : "v"(vp + 32 * SEQ));
  };
  auto stage = [&](int nb) {
    #pragma unroll
    for (int cc = 0; cc < 2; ++cc) {
      int row = srow + 32 * cc;                  // kv row for K, d row for V^T
      *reinterpret_cast<u32x4*>(&sK[nb][row * SKS + ((sslot ^ (row >> 3)) << 3)]) = kr[cc];
      *reinterpret_cast<u32x4*>(&sV[nb][row * SKS + ((sslot ^ (row >> 3)) << 3)]) = vr[cc];
    }
  };

  float mrun = -1e30f, lrun = 0.f;
  f32x16 accO[2] = {};

  issue(0);
  asm volatile("s_waitcnt vmcnt(0)" ::: "memory");
  stage(0);
  issue(1);
  asm volatile("s_waitcnt lgkmcnt(0)" ::: "memory");
  __builtin_amdgcn_s_barrier();
  asm volatile("" ::: "memory");

  for (int t = 0; t < nt; ++t) {
    const int c = t & 1;
    if (t + 1 < nt) {
      asm volatile("s_waitcnt vmcnt(0)" ::: "memory");
      stage(c ^ 1);
      if (t + 2 < nt) issue(t + 2);
    }
    const bool masked = (t * AKV + AKV - 1 > qbase);
    #pragma unroll
    for (int sub = 0; sub < 2; ++sub) {
      f32x16 sc = {};
      __builtin_amdgcn_s_setprio(1);
      #pragma unroll
      for (int kt = 0; kt < 4; ++kt) {
        int krow = 32 * sub + l31;
        bf16x8 kf = *reinterpret_cast<const bf16x8*>(
            &sK[c][krow * SKS + (((2 * kt + hi) ^ (krow >> 3)) << 3)]);
        sc = __builtin_amdgcn_mfma_f32_32x32x16_bf16(kf, qf[kt], sc, 0, 0, 0);
      }
      __builtin_amdgcn_s_setprio(0);

      float p[16];
      const int qa = qbase + l31;
      const int kb0 = t * AKV + 32 * sub + 4 * hi;
      #pragma unroll
      for (int r = 0; r < 16; ++r) {
        float s = sc[r];
        if (masked) {
          int kvi = kb0 + (r & 3) + 8 * (r >> 2);
          if (kvi > qa) s = -1e30f;
        }
        p[r] = s;
      }
      float m0 = fmaxf(fmaxf(p[0],  p[1]),  p[2]);
      float m1 = fmaxf(fmaxf(p[3],  p[4]),  p[5]);
      float m2 = fmaxf(fmaxf(p[6],  p[7]),  p[8]);
      float m3 = fmaxf(fmaxf(p[9],  p[10]), p[11]);
      float m4 = fmaxf(fmaxf(p[12], p[13]), p[14]);
      float mt = fmaxf(fmaxf(fmaxf(m0, m1), fmaxf(m2, m3)), fmaxf(m4, p[15]));
      mt = fmaxf(mt, __shfl_xor(mt, 32));
      if (!__all(mt <= mrun + 11.54f)) {
        float mnew = fmaxf(mrun, mt);
        float scl = fexp2(mrun - mnew);
        mrun = mnew;
        lrun *= scl;
        #pragma unroll
        for (int i = 0; i < 16; ++i) { accO[0][i] *= scl; accO[1][i] *= scl; }
      }
      float rs = 0.f;
      #pragma unroll
      for (int r = 0; r < 16; ++r) { p[r] = fexp2(p[r] - mrun); rs += p[r]; }
      lrun += rs + __shfl_xor(rs, 32);

      bf16x8 pf[2];
      #pragma unroll
      for (int kt = 0; kt < 2; ++kt) {
        unsigned P01 = packbf(p[8*kt+0], p[8*kt+1]);
        unsigned P23 = packbf(p[8*kt+2], p[8*kt+3]);
        unsigned P45 = packbf(p[8*kt+4], p[8*kt+5]);
        unsigned P67 = packbf(p[8*kt+6], p[8*kt+7]);
        unsigned ra = __shfl_xor(hi == 0 ? P45 : P01, 32);
        unsigned rb = __shfl_xor(hi == 0 ? P67 : P23, 32);
        unsigned dw0 = hi == 0 ? P01 : ra;
        unsigned dw1 = hi == 0 ? P23 : rb;
        unsigned dw2 = hi == 0 ? ra : P45;
        unsigned dw3 = hi == 0 ? rb : P67;
        pf[kt] = __builtin_bit_cast(bf16x8, (u32x4){dw0, dw1, dw2, dw3});
      }

      __builtin_amdgcn_s_setprio(1);
      #pragma unroll
      for (int dt = 0; dt < 2; ++dt) {
        #pragma unroll
        for (int kt = 0; kt < 2; ++kt) {
          int vrow = 32 * dt + l31;
          bf16x8 vf = *reinterpret_cast<const bf16x8*>(
              &sV[c][vrow * SKS + (((4 * sub + 2 * kt + hi) ^ (vrow >> 3)) << 3)]);
          accO[dt] = __builtin_amdgcn_mfma_f32_32x32x16_bf16(vf, pf[kt], accO[dt], 0, 0, 0);
        }
      }
      __builtin_amdgcn_s_setprio(0);
    }
    asm volatile("s_waitcnt lgkmcnt(0)" ::: "memory");
    __builtin_amdgcn_s_barrier();
    asm volatile("" ::: "memory");
  }

  bf16_t* sOw = &sK[0][0] + w * (32 * SKS);
  float inv = 1.f / lrun;
  #pragma unroll
  for (int dt = 0; dt < 2; ++dt)
    #pragma unroll
    for (int r = 0; r < 16; ++r) {
      int d = 32 * dt + (r & 3) + 8 * (r >> 2) + 4 * hi;
      sOw[l31 * SKS + (d ^ ((l31 >> 3) << 3))] = (bf16_t)(accO[dt][r] * inv);
    }
  #pragma unroll
  for (int i = 0; i < 4; ++i) {
    int qr = 8 * i + (lane >> 3);
    int ch = lane & 7;
    bf16x8 vvv = *reinterpret_cast<const bf16x8*>(
        &sOw[qr * SKS + ((ch ^ (qr >> 3)) << 3)]);
    *reinterpret_cast<bf16x8*>(
        O + ((size_t)(b * SEQ + qbase + qr)) * DIMM + h * HDIM + ch * 8) = vvv;
  }
}

// ---------------------------------------------------------------------------
extern "C" void kernel_launch(void* const* d_in, const int* in_sizes, int n_in,
                              void* d_out, int out_size, void* d_ws, size_t ws_size,
                              hipStream_t stream) {
  const float* x     = (const float*)d_in[0];
  // d_in[1] = mask (causal tril) — structure hardcoded
  const float* qkv_w = (const float*)d_in[2];
  const float* qkv_b = (const float*)d_in[3];
  const float* out_w = (const float*)d_in[4];
  const float* out_b = (const float*)d_in[5];
  float* out = (float*)d_out;

  char* ws = (char*)d_ws;
  size_t off = 0;
  auto alloc = [&](size_t bytes) {
    char* p = ws + off;
    off += (bytes + 255) & ~(size_t)255;
    return (void*)p;
  };
  bf16_t* Xb    = (bf16_t*)alloc((size_t)MROWS * DIMM * 2);
  bf16_t* WqkvT = (bf16_t*)alloc((size_t)3 * DIMM * DIMM * 2);
  bf16_t* WoutT = (bf16_t*)alloc((size_t)DIMM * DIMM * 2);
  bf16_t* Qh    = (bf16_t*)alloc((size_t)64 * SEQ * HDIM * 2);
  bf16_t* Kh    = (bf16_t*)alloc((size_t)64 * SEQ * HDIM * 2);
  bf16_t* Vth   = (bf16_t*)alloc((size_t)64 * HDIM * SEQ * 2);  // V^T [bh][d][t]
  bf16_t* AO    = (bf16_t*)alloc((size_t)MROWS * DIMM * 2);
  float*  cosT  = (float*)alloc((size_t)SEQ * 32 * 4);
  float*  sinT  = (float*)alloc((size_t)SEQ * 32 * 4);

  k_convert<<<(MROWS * DIMM / 4 + 255) / 256, 256, 0, stream>>>(x, Xb, MROWS * DIMM / 4);
  k_transpose_convert<<<dim3(3 * DIMM / 32, DIMM / 32), dim3(32, 8), 0, stream>>>(qkv_w, WqkvT, DIMM, 3 * DIMM);
  k_transpose_convert<<<dim3(DIMM / 32, DIMM / 32), dim3(32, 8), 0, stream>>>(out_w, WoutT, DIMM, DIMM);
  k_rope_table<<<(SEQ * 32 + 255) / 256, 256, 0, stream>>>(cosT, sinT);

  k_gemm0<<<dim3(3 * DIMM / 256, MROWS / 256), 512, 0, stream>>>(
      Xb, WqkvT, qkv_b, Qh, Kh, Vth, cosT, sinT);

  k_attn<<<dim3(NP * 64), 256, 0, stream>>>(Qh, Kh, Vth, AO);

  k_gemm1<<<dim3(DIMM / 128, MROWS / 128), 256, 0, stream>>>(
      AO, WoutT, out_b, out, MROWS, DIMM, DIMM);
}

// Round 12
// 194.128 us; speedup vs baseline: 1.2960x; 1.0074x over previous
//
#include <hip/hip_runtime.h>

typedef __bf16 bf16_t;
typedef __bf16 bf16x8 __attribute__((ext_vector_type(8)));
typedef float  f32x4  __attribute__((ext_vector_type(4)));
typedef float  f32x16 __attribute__((ext_vector_type(16)));
typedef unsigned u32x4 __attribute__((ext_vector_type(4)));

#define DIMM  1024
#define NHEAD 16
#define HDIM  64
#define BATCH 4
#define SEQ   2048
#define MROWS (BATCH*SEQ)   // 8192

#define AQB   128           // q rows per attn block
#define AKV   64            // kv per tile
#define NP    (SEQ/AQB)     // 16 q-blocks
#define SKS   72            // LDS row stride (elems), 144B, 16B-aligned
#define LOG2E 1.44269504088896f

__device__ __forceinline__ void gload_lds16(const bf16_t* g, bf16_t* l) {
  __builtin_amdgcn_global_load_lds(
      (const __attribute__((address_space(1))) void*)g,
      (__attribute__((address_space(3))) void*)l, 16, 0, 0);
}

__device__ __forceinline__ unsigned short f2bu(float f) {
  bf16_t b = (bf16_t)f;
  return __builtin_bit_cast(unsigned short, b);
}
__device__ __forceinline__ float bu2f(unsigned short u) {
  return __uint_as_float(((unsigned)u) << 16);
}
__device__ __forceinline__ unsigned packbf(float a, float b) {
  return (unsigned)f2bu(a) | ((unsigned)f2bu(b) << 16);
}
__device__ __forceinline__ float fexp2(float x) {   // v_exp_f32 = 2^x
  float r; asm("v_exp_f32 %0, %1" : "=v"(r) : "v"(x)); return r;
}

// ---------------- fp32 -> bf16 flat convert (4 elems/thread) ----------------
__global__ void k_convert(const float* __restrict__ in, bf16_t* __restrict__ out, int n4) {
  int i = blockIdx.x * blockDim.x + threadIdx.x;
  if (i >= n4) return;
  float4 v = reinterpret_cast<const float4*>(in)[i];
  ushort4 o;
  o.x = f2bu(v.x); o.y = f2bu(v.y); o.z = f2bu(v.z); o.w = f2bu(v.w);
  reinterpret_cast<ushort4*>(out)[i] = o;
}

// ------------- fp32 [R][C] -> bf16 [C][R] tiled transpose-convert -----------
__global__ void k_transpose_convert(const float* __restrict__ in, bf16_t* __restrict__ out,
                                    int R, int C) {
  __shared__ float tile[32][33];
  int cb = blockIdx.x * 32, rb = blockIdx.y * 32;
  int tx = threadIdx.x, ty = threadIdx.y;
  #pragma unroll
  for (int i = 0; i < 4; ++i)
    tile[ty + i*8][tx] = in[(size_t)(rb + ty + i*8) * C + cb + tx];
  __syncthreads();
  #pragma unroll
  for (int i = 0; i < 4; ++i)
    out[(size_t)(cb + ty + i*8) * R + rb + tx] = (bf16_t)tile[tx][ty + i*8];
}

// ---------------- RoPE cos/sin table [SEQ][32], fp64 trig ------------------
__global__ void k_rope_table(float* __restrict__ cosT, float* __restrict__ sinT) {
  int id = blockIdx.x * blockDim.x + threadIdx.x;
  if (id >= SEQ * 32) return;
  int t = id >> 5, i = id & 31;
  double ang = (double)t * pow(10000.0, -(double)i / 32.0);
  cosT[id] = (float)cos(ang);
  sinT[id] = (float)sin(ang);
}

// ---------- 256x256 8-phase bf16 GEMM, QKV projection (M=8192 N=3072 K=1024)
// 8-phase T2+T3+T4+T5 schedule (see R9). Epilogue is layout-aware:
//   bx<4 : Q -> rope + 0.125*log2e scale -> head layout [bh][t][d]
//   bx<8 : K -> rope -> head layout
//   else : V -> TRANSPOSED [bh][d][t], ushort4-packed stores.
// Rope pair exchange = __shfl_xor(val,1) (adjacent-lane DPP); bias pre-rope.
__global__ __launch_bounds__(512, 2) void k_gemm0(
    const bf16_t* __restrict__ A, const bf16_t* __restrict__ BT,
    const float* __restrict__ bias,
    bf16_t* __restrict__ q, bf16_t* __restrict__ k, bf16_t* __restrict__ vt,
    const float* __restrict__ cosT, const float* __restrict__ sinT)
{
  __shared__ bf16_t sA[2][2][128 * 64];   // [buf][khalf]
  __shared__ bf16_t sB[2][2][128 * 64];

  const int tid = threadIdx.x;
  const int w = tid >> 6;
  const int lane = tid & 63;
  const int wm = w >> 2, wn = w & 3;       // 2M x 4N waves
  const int l15 = lane & 15, l4 = lane >> 4;

  // bijective XCD swizzle (nwg = 384, multiple of 8)
  int nwg = gridDim.x * gridDim.y;
  int id  = blockIdx.y * gridDim.x + blockIdx.x;
  int cpx = nwg >> 3;
  int sid = (id & 7) * cpx + (id >> 3);
  int bx = sid % gridDim.x, by = sid / gridDim.x;
  const int rowA0 = by * 256, colB0 = bx * 256;

  f32x4 acc[8][4] = {};
  bf16x8 bf_[4];

  auto stage = [&](int tile, int part) {   // part: 0=A.k0 1=B.k0 2=A.k1 3=B.k1
    if (tile >= 16) return;
    const int kh = part >> 1;
    const bool isB = part & 1;
    const bf16_t* src = isB ? BT : A;
    const int r0 = isB ? colB0 : rowA0;
    bf16_t* dst = (isB ? &sB[0][0][0] : &sA[0][0][0]) + ((tile & 1) * 2 + kh) * (128 * 64);
    #pragma unroll
    for (int call = 0; call < 2; ++call) {
      int n = call * 512 + tid;
      int R = n >> 3, slot = n & 7;
      int sp = slot ^ (R & 7);
      int row = R * 2 + (sp >> 2);
      gload_lds16(src + (size_t)(r0 + row) * 1024 + tile * 64 + kh * 32 + (sp & 3) * 8,
                  dst + n * 8);
    }
  };

  auto rdA = [&](int bc, int kh, int mfa) -> bf16x8 {
    int row = wm * 128 + mfa * 16 + l15;
    int R = row >> 1;
    int slot = (((row & 1) << 2) | l4) ^ (R & 7);
    return *reinterpret_cast<const bf16x8*>(&sA[bc][kh][R * 64 + slot * 8]);
  };
  auto rdB = [&](int bc, int kh, int nf) -> bf16x8 {
    int row = wn * 64 + nf * 16 + l15;
    int R = row >> 1;
    int slot = (((row & 1) << 2) | l4) ^ (R & 7);
    return *reinterpret_cast<const bf16x8*>(&sB[bc][kh][R * 64 + slot * 8]);
  };

  auto phase = [&](int bc, int kh, int mh, int stile, int spart, int wait_n) {
    bf16x8 af[4];
    if (mh == 0) {
      #pragma unroll
      for (int nf = 0; nf < 4; ++nf) bf_[nf] = rdB(bc, kh, nf);
    }
    #pragma unroll
    for (int mf = 0; mf < 4; ++mf) af[mf] = rdA(bc, kh, mh * 4 + mf);
    stage(stile, spart);
    if (wait_n == 4)      asm volatile("s_waitcnt vmcnt(4)" ::: "memory");
    else if (wait_n == 0) asm volatile("s_waitcnt vmcnt(0)" ::: "memory");
    __builtin_amdgcn_s_barrier();
    __builtin_amdgcn_s_setprio(1);
    #pragma unroll
    for (int mf = 0; mf < 4; ++mf)
      #pragma unroll
      for (int nf = 0; nf < 4; ++nf)
        acc[mh * 4 + mf][nf] = __builtin_amdgcn_mfma_f32_16x16x32_bf16(
            af[mf], bf_[nf], acc[mh * 4 + mf][nf], 0, 0, 0);
    __builtin_amdgcn_s_setprio(0);
    __builtin_amdgcn_s_barrier();
  };

  // prologue: tile0 fully + tile1 k0-halves; wait all but newest 2 half-tiles
  stage(0, 0); stage(0, 1); stage(0, 2); stage(0, 3);
  stage(1, 0); stage(1, 1);
  asm volatile("s_waitcnt vmcnt(4)" ::: "memory");
  __builtin_amdgcn_s_barrier();

  for (int i = 0; i < 8; ++i) {
    const int t0 = 2 * i, t1 = 2 * i + 1;
    phase(0, 0, 0, t1,     2, -1);
    phase(0, 0, 1, t1,     3, -1);
    phase(0, 1, 0, t0 + 2, 0, -1);
    phase(0, 1, 1, t0 + 2, 1, (t0 + 2 < 16) ? 4 : 0);
    phase(1, 0, 0, t0 + 2, 2, -1);
    phase(1, 0, 1, t0 + 2, 3, -1);
    phase(1, 1, 0, t0 + 3, 0, -1);
    phase(1, 1, 1, t0 + 3, 1, (t0 + 3 < 16) ? 4 : 0);
  }

  // ---- epilogue ----
  const bool isV = (bx >= 8);
  const bool isQ = (bx < 4);
  const float qs = 0.125f * LOG2E;
  if (isV) {
    #pragma unroll
    for (int mfa = 0; mfa < 8; ++mfa) {
      #pragma unroll
      for (int nf = 0; nf < 4; ++nf) {
        int n = colB0 + wn * 64 + nf * 16 + l15;
        int h = (n >> 6) & 15, d = n & 63;
        float bs = bias[n];
        int m0 = rowA0 + wm * 128 + mfa * 16 + l4 * 4;
        int b = m0 >> 11, t = m0 & 2047;
        ushort4 pk;
        pk.x = f2bu(acc[mfa][nf][0] + bs);
        pk.y = f2bu(acc[mfa][nf][1] + bs);
        pk.z = f2bu(acc[mfa][nf][2] + bs);
        pk.w = f2bu(acc[mfa][nf][3] + bs);
        *reinterpret_cast<ushort4*>(
            vt + ((size_t)((b * NHEAD + h) * HDIM + d)) * SEQ + t) = pk;
      }
    }
  } else {
    bf16_t* dst = isQ ? q : k;
    #pragma unroll
    for (int mfa = 0; mfa < 8; ++mfa) {
      #pragma unroll
      for (int nf = 0; nf < 4; ++nf) {
        int n = colB0 + wn * 64 + nf * 16 + l15;
        int h = (n >> 6) & 15, d = n & 63;
        int i2 = d >> 1;
        float bs = bias[n];
        #pragma unroll
        for (int r = 0; r < 4; ++r) {
          int m = rowA0 + wm * 128 + mfa * 16 + l4 * 4 + r;
          int b = m >> 11, t = m & 2047;
          float val = acc[mfa][nf][r] + bs;
          float prt = __shfl_xor(val, 1);    // partner within the rope pair
          float c = cosT[(t << 5) + i2], s = sinT[(t << 5) + i2];
          float y = (d & 1) ? (val * c + prt * s) : (val * c - prt * s);
          if (isQ) y *= qs;                  // exp2-domain softmax scale
          dst[((size_t)(b * NHEAD + h) * SEQ + t) * HDIM + d] = (bf16_t)y;
        }
      }
    }
  }
}

// --------------- 128x128 bf16 GEMM (out-proj): fp32 out [M][N] -------------
__global__ __launch_bounds__(256) void k_gemm1(
    const bf16_t* __restrict__ A, const bf16_t* __restrict__ BT,
    const float* __restrict__ bias, float* __restrict__ outf, int M, int N, int K)
{
  __shared__ bf16_t sA[128 * 32];
  __shared__ bf16_t sB[128 * 32];
  const int tid = threadIdx.x;
  const int w = tid >> 6, lane = tid & 63;
  const int wr = w >> 1, wc = w & 1;
  const int l15 = lane & 15, l4 = lane >> 4;

  int nwg = gridDim.x * gridDim.y;
  int id  = blockIdx.y * gridDim.x + blockIdx.x;
  int cpx = nwg >> 3;
  int sid = (id & 7) * cpx + (id >> 3);
  int bx = sid % gridDim.x, by = sid / gridDim.x;

  const int rowA0 = by * 128;
  const int colB0 = bx * 128;

  f32x4 acc[4][4] = {};

  const int nkt = K >> 5;
  for (int kt = 0; kt < nkt; ++kt) {
    __syncthreads();
    #pragma unroll
    for (int i = 0; i < 2; ++i) {
      int c = i * 256 + w * 64 + lane;
      int row = c >> 2, k8 = (c & 3) * 8;
      gload_lds16(A  + (size_t)(rowA0 + row) * K + kt * 32 + k8, sA + (i * 256 + w * 64) * 8);
      gload_lds16(BT + (size_t)(colB0 + row) * K + kt * 32 + k8, sB + (i * 256 + w * 64) * 8);
    }
    asm volatile("s_waitcnt vmcnt(0)" ::: "memory");
    __syncthreads();
    bf16x8 af[4], bfr[4];
    #pragma unroll
    for (int mi = 0; mi < 4; ++mi)
      af[mi] = *reinterpret_cast<const bf16x8*>(sA + (wr * 64 + mi * 16 + l15) * 32 + l4 * 8);
    #pragma unroll
    for (int ni = 0; ni < 4; ++ni)
      bfr[ni] = *reinterpret_cast<const bf16x8*>(sB + (wc * 64 + ni * 16 + l15) * 32 + l4 * 8);
    #pragma unroll
    for (int mi = 0; mi < 4; ++mi)
      #pragma unroll
      for (int ni = 0; ni < 4; ++ni)
        acc[mi][ni] = __builtin_amdgcn_mfma_f32_16x16x32_bf16(af[mi], bfr[ni], acc[mi][ni], 0, 0, 0);
  }

  #pragma unroll
  for (int mi = 0; mi < 4; ++mi) {
    #pragma unroll
    for (int ni = 0; ni < 4; ++ni) {
      int n = colB0 + wc * 64 + ni * 16 + l15;
      float bs = bias[n];
      #pragma unroll
      for (int r = 0; r < 4; ++r) {
        int m = rowA0 + wr * 64 + mi * 16 + l4 * 4 + r;
        outf[(size_t)m * N + n] = acc[mi][ni][r] + bs;
      }
    }
  }
}

// ------------- causal flash attention: swapped-operand 32x32 ----------------
// As R11, but the KV loop is UNROLLED BY 2 with STATIC buffer indices (nt is
// always even): R11 showed VGPR_Count=64 -- the compiler rematerializes all
// swizzled LDS addresses every tile because sK[c]/sV[c] has a runtime index.
// With literal c per body copy, addresses are loop-invariant and hoistable.
#define ATTN_BODY(CBUF, T)                                                     \
  do {                                                                         \
    const int t_ = (T);                                                        \
    if (t_ + 1 < nt) {                                                         \
      asm volatile("s_waitcnt vmcnt(0)" ::: "memory");                         \
      stage(CBUF ^ 1);                                                         \
      if (t_ + 2 < nt) issue(t_ + 2);                                          \
    }                                                                          \
    const bool masked = (t_ * AKV + AKV - 1 > qbase);                          \
    _Pragma("unroll")                                                          \
    for (int sub = 0; sub < 2; ++sub) {                                        \
      f32x16 sc = {};                                                          \
      __builtin_amdgcn_s_setprio(1);                                           \
      _Pragma("unroll")                                                        \
      for (int kt = 0; kt < 4; ++kt) {                                         \
        int krow = 32 * sub + l31;                                             \
        bf16x8 kf = *reinterpret_cast<const bf16x8*>(                          \
            &sK[CBUF][krow * SKS + (((2 * kt + hi) ^ (krow >> 3)) << 3)]);     \
        sc = __builtin_amdgcn_mfma_f32_32x32x16_bf16(kf, qf[kt], sc, 0, 0, 0); \
      }                                                                        \
      __builtin_amdgcn_s_setprio(0);                                           \
      float p[16];                                                             \
      const int qa = qbase + l31;                                              \
      const int kb0 = t_ * AKV + 32 * sub + 4 * hi;                            \
      _Pragma("unroll")                                                        \
      for (int r = 0; r < 16; ++r) {                                           \
        float s = sc[r];                                                       \
        if (masked) {                                                          \
          int kvi = kb0 + (r & 3) + 8 * (r >> 2);                              \
          if (kvi > qa) s = -1e30f;                                            \
        }                                                                      \
        p[r] = s;                                                              \
      }                                                                        \
      float m0 = fmaxf(fmaxf(p[0],  p[1]),  p[2]);                             \
      float m1 = fmaxf(fmaxf(p[3],  p[4]),  p[5]);                             \
      float m2 = fmaxf(fmaxf(p[6],  p[7]),  p[8]);                             \
      float m3 = fmaxf(fmaxf(p[9],  p[10]), p[11]);                            \
      float m4 = fmaxf(fmaxf(p[12], p[13]), p[14]);                            \
      float mt = fmaxf(fmaxf(fmaxf(m0, m1), fmaxf(m2, m3)), fmaxf(m4, p[15]));\
      mt = fmaxf(mt, __shfl_xor(mt, 32));                                      \
      if (!__all(mt <= mrun + 11.54f)) {                                       \
        float mnew = fmaxf(mrun, mt);                                          \
        float scl = fexp2(mrun - mnew);                                        \
        mrun = mnew;                                                           \
        lrun *= scl;                                                           \
        _Pragma("unroll")                                                      \
        for (int i = 0; i < 16; ++i) { accO[0][i] *= scl; accO[1][i] *= scl; } \
      }                                                                        \
      float rs = 0.f;                                                          \
      _Pragma("unroll")                                                        \
      for (int r = 0; r < 16; ++r) { p[r] = fexp2(p[r] - mrun); rs += p[r]; }  \
      lrun += rs + __shfl_xor(rs, 32);                                         \
      bf16x8 pf[2];                                                            \
      _Pragma("unroll")                                                        \
      for (int kt = 0; kt < 2; ++kt) {                                         \
        unsigned P01 = packbf(p[8*kt+0], p[8*kt+1]);                           \
        unsigned P23 = packbf(p[8*kt+2], p[8*kt+3]);                           \
        unsigned P45 = packbf(p[8*kt+4], p[8*kt+5]);                           \
        unsigned P67 = packbf(p[8*kt+6], p[8*kt+7]);                           \
        unsigned ra = __shfl_xor(hi == 0 ? P45 : P01, 32);                     \
        unsigned rb = __shfl_xor(hi == 0 ? P67 : P23, 32);                     \
        unsigned dw0 = hi == 0 ? P01 : ra;                                     \
        unsigned dw1 = hi == 0 ? P23 : rb;                                     \
        unsigned dw2 = hi == 0 ? ra : P45;                                     \
        unsigned dw3 = hi == 0 ? rb : P67;                                     \
        pf[kt] = __builtin_bit_cast(bf16x8, (u32x4){dw0, dw1, dw2, dw3});      \
      }                                                                        \
      __builtin_amdgcn_s_setprio(1);                                           \
      _Pragma("unroll")                                                        \
      for (int dt = 0; dt < 2; ++dt) {                                         \
        _Pragma("unroll")                                                      \
        for (int kt = 0; kt < 2; ++kt) {                                       \
          int vrow = 32 * dt + l31;                                            \
          bf16x8 vf = *reinterpret_cast<const bf16x8*>(                        \
              &sV[CBUF][vrow * SKS + (((4 * sub + 2 * kt + hi) ^ (vrow >> 3)) << 3)]); \
          accO[dt] = __builtin_amdgcn_mfma_f32_32x32x16_bf16(vf, pf[kt], accO[dt], 0, 0, 0); \
        }                                                                      \
      }                                                                        \
      __builtin_amdgcn_s_setprio(0);                                           \
    }                                                                          \
    asm volatile("s_waitcnt lgkmcnt(0)" ::: "memory");                         \
    __builtin_amdgcn_s_barrier();                                              \
    asm volatile("" ::: "memory");                                             \
  } while (0)

__global__ __launch_bounds__(256, 2) void k_attn(
    const bf16_t* __restrict__ Q, const bf16_t* __restrict__ Kb,
    const bf16_t* __restrict__ Vt, bf16_t* __restrict__ O)
{
  __shared__ bf16_t sK[2][64 * SKS];
  __shared__ bf16_t sV[2][64 * SKS];   // V^T: [d][kv]

  const int tid = threadIdx.x;
  const int w = tid >> 6, lane = tid & 63;
  const int l31 = lane & 31, hi = lane >> 5;

  const int id = blockIdx.x;
  const int j4 = id >> 8;            // dispatch quartile (longest first)
  const int k4 = (id >> 6) & 3;
  const int bh = id & 63;
  const int qblk = (j4 == 0) ? 15 - 2 * k4
                 : (j4 == 1) ? 2 * k4
                 : (j4 == 2) ? 14 - 2 * k4
                 :             2 * k4 + 1;

  const size_t hbase = (size_t)bh * SEQ * HDIM;
  const int b = bh >> 4, h = bh & 15;
  const int srow = tid >> 3, sslot = tid & 7;

  const int qbase = qblk * AQB + 32 * w;
  const int nt = 2 * qblk + 2;       // always even

  bf16x8 qf[4];
  #pragma unroll
  for (int kt = 0; kt < 4; ++kt)
    qf[kt] = *reinterpret_cast<const bf16x8*>(
        Q + hbase + (size_t)(qbase + l31) * HDIM + kt * 16 + hi * 8);
  asm volatile("s_waitcnt vmcnt(0)" ::: "memory");
  asm volatile("" : "+v"(qf[0]), "+v"(qf[1]), "+v"(qf[2]), "+v"(qf[3]));

  u32x4 kr[2], vr[2];
  auto issue = [&](int t) {
    const bf16_t* kp = Kb + hbase + (size_t)(t * AKV + srow) * HDIM + sslot * 8;
    const bf16_t* vp = Vt + hbase + (size_t)srow * SEQ + t * AKV + sslot * 8;
    asm volatile("global_load_dwordx4 %0, %1, off" : "=v"(kr[0]) : "v"(kp));
    asm volatile("global_load_dwordx4 %0, %1, off" : "=v"(kr[1]) : "v"(kp + 32 * HDIM));
    asm volatile("global_load_dwordx4 %0, %1, off" : "=v"(vr[0]) : "v"(vp));
    asm volatile("global_load_dwordx4 %0, %1, off" : "=v"(vr[1]) : "v"(vp + 32 * SEQ));
  };
  auto stage = [&](int nb) {
    #pragma unroll
    for (int cc = 0; cc < 2; ++cc) {
      int row = srow + 32 * cc;                  // kv row for K, d row for V^T
      *reinterpret_cast<u32x4*>(&sK[nb][row * SKS + ((sslot ^ (row >> 3)) << 3)]) = kr[cc];
      *reinterpret_cast<u32x4*>(&sV[nb][row * SKS + ((sslot ^ (row >> 3)) << 3)]) = vr[cc];
    }
  };

  float mrun = -1e30f, lrun = 0.f;
  f32x16 accO[2] = {};

  issue(0);
  asm volatile("s_waitcnt vmcnt(0)" ::: "memory");
  stage(0);
  issue(1);
  asm volatile("s_waitcnt lgkmcnt(0)" ::: "memory");
  __builtin_amdgcn_s_barrier();
  asm volatile("" ::: "memory");

  for (int tt = 0; tt < nt; tt += 2) {
    ATTN_BODY(0, tt);
    ATTN_BODY(1, tt + 1);
  }

  bf16_t* sOw = &sK[0][0] + w * (32 * SKS);
  float inv = 1.f / lrun;
  #pragma unroll
  for (int dt = 0; dt < 2; ++dt)
    #pragma unroll
    for (int r = 0; r < 16; ++r) {
      int d = 32 * dt + (r & 3) + 8 * (r >> 2) + 4 * hi;
      sOw[l31 * SKS + (d ^ ((l31 >> 3) << 3))] = (bf16_t)(accO[dt][r] * inv);
    }
  #pragma unroll
  for (int i = 0; i < 4; ++i) {
    int qr = 8 * i + (lane >> 3);
    int ch = lane & 7;
    bf16x8 vvv = *reinterpret_cast<const bf16x8*>(
        &sOw[qr * SKS + ((ch ^ (qr >> 3)) << 3)]);
    *reinterpret_cast<bf16x8*>(
        O + ((size_t)(b * SEQ + qbase + qr)) * DIMM + h * HDIM + ch * 8) = vvv;
  }
}

// ---------------------------------------------------------------------------
extern "C" void kernel_launch(void* const* d_in, const int* in_sizes, int n_in,
                              void* d_out, int out_size, void* d_ws, size_t ws_size,
                              hipStream_t stream) {
  const float* x     = (const float*)d_in[0];
  // d_in[1] = mask (causal tril) — structure hardcoded
  const float* qkv_w = (const float*)d_in[2];
  const float* qkv_b = (const float*)d_in[3];
  const float* out_w = (const float*)d_in[4];
  const float* out_b = (const float*)d_in[5];
  float* out = (float*)d_out;

  char* ws = (char*)d_ws;
  size_t off = 0;
  auto alloc = [&](size_t bytes) {
    char* p = ws + off;
    off += (bytes + 255) & ~(size_t)255;
    return (void*)p;
  };
  bf16_t* Xb    = (bf16_t*)alloc((size_t)MROWS * DIMM * 2);
  bf16_t* WqkvT = (bf16_t*)alloc((size_t)3 * DIMM * DIMM * 2);
  bf16_t* WoutT = (bf16_t*)alloc((size_t)DIMM * DIMM * 2);
  bf16_t* Qh    = (bf16_t*)alloc((size_t)64 * SEQ * HDIM * 2);
  bf16_t* Kh    = (bf16_t*)alloc((size_t)64 * SEQ * HDIM * 2);
  bf16_t* Vth   = (bf16_t*)alloc((size_t)64 * HDIM * SEQ * 2);  // V^T [bh][d][t]
  bf16_t* AO    = (bf16_t*)alloc((size_t)MROWS * DIMM * 2);
  float*  cosT  = (float*)alloc((size_t)SEQ * 32 * 4);
  float*  sinT  = (float*)alloc((size_t)SEQ * 32 * 4);

  k_convert<<<(MROWS * DIMM / 4 + 255) / 256, 256, 0, stream>>>(x, Xb, MROWS * DIMM / 4);
  k_transpose_convert<<<dim3(3 * DIMM / 32, DIMM / 32), dim3(32, 8), 0, stream>>>(qkv_w, WqkvT, DIMM, 3 * DIMM);
  k_transpose_convert<<<dim3(DIMM / 32, DIMM / 32), dim3(32, 8), 0, stream>>>(out_w, WoutT, DIMM, DIMM);
  k_rope_table<<<(SEQ * 32 + 255) / 256, 256, 0, stream>>>(cosT, sinT);

  k_gemm0<<<dim3(3 * DIMM / 256, MROWS / 256), 512, 0, stream>>>(
      Xb, WqkvT, qkv_b, Qh, Kh, Vth, cosT, sinT);

  k_attn<<<dim3(NP * 64), 256, 0, stream>>>(Qh, Kh, Vth, AO);

  k_gemm1<<<dim3(DIMM / 128, MROWS / 128), 256, 0, stream>>>(
      AO, WoutT, out_b, out, MROWS, DIMM, DIMM);
}